// Round 11
// baseline (665.442 us; speedup 1.0000x reference)
//
#include <hip/hip_runtime.h>
#include <hip/hip_bf16.h>

typedef __hip_bfloat16 bf16;
typedef short s8v __attribute__((ext_vector_type(8)));
typedef float f4v __attribute__((ext_vector_type(4)));

__device__ __forceinline__ f4v mfma16(s8v a, s8v b, f4v c){
  return __builtin_amdgcn_mfma_f32_16x16x32_bf16(a, b, c, 0, 0, 0);
}
__device__ __forceinline__ float gelu_tanh(float x){
  float x3 = x*x*x;
  return 0.5f*x*(1.0f + tanhf(0.7978845608028654f*(x + 0.044715f*x3)));
}

// ---------------- sentinel fill (encodes ws_size in MB * 16) ----------------
__global__ void k_fill(float* out, int n, float val){
  int i = blockIdx.x*256 + threadIdx.x;
  if (i < n) out[i] = val;
}

// ---------------- weight prep ----------------
__global__ __launch_bounds__(256) void k_prep(const float* __restrict__ Wk, const float* __restrict__ Wq,
                       const float* __restrict__ c1wf,
                       bf16* __restrict__ Wkt, bf16* __restrict__ Wqt, bf16* __restrict__ c1w){
  int tid = blockIdx.x*256 + threadIdx.x; // 98304 total
  if (tid < 32768){ int d = tid >> 7, j = tid & 127; Wkt[tid] = __float2bfloat16(Wk[j*256 + d]); }
  else if (tid < 65536){ int r = tid - 32768; int d = r >> 7, j = r & 127; Wqt[r] = __float2bfloat16(Wq[j*256 + d]); }
  else { int r = tid - 65536; c1w[r] = __float2bfloat16(c1wf[r]); }
}

// ---------------- fused patchify (one batch, all 4 tensors) ----------------
__global__ __launch_bounds__(256) void k_patch4(const float* __restrict__ k0, const float* __restrict__ k1,
                         const float* __restrict__ q0, const float* __restrict__ q1,
                         bf16* __restrict__ Kp, bf16* __restrict__ Qp, bf16* __restrict__ Vt){
  __shared__ float tile[64][33];
  int gy = blockIdx.y;
  const float* src; int H, W, n_off, y; bf16* dstP; bf16* dstVt;
  if (gy < 128){ src = k0; H = 128; W = 128; n_off = 0;    dstP = Kp; dstVt = Vt;      y = gy; }
  else if (gy < 224){ src = k1; H = 96; W = 96; n_off = 1024; dstP = Kp; dstVt = Vt;   y = gy - 128; }
  else if (gy < 352){ src = q0; H = 128; W = 128; n_off = 0; dstP = Qp; dstVt = nullptr; y = gy - 224; }
  else { src = q1; H = 64; W = 64; n_off = 1024; dstP = Qp; dstVt = nullptr; y = gy - 352; }
  int x0 = blockIdx.x*32;
  if (x0 >= W) return;
  int t = threadIdx.x;
  const float* sp = src + (size_t)y*W + x0;
  size_t HW = (size_t)H*W;
#pragma unroll
  for (int r = 0; r < 8; r++){
    int idx = t + 256*r; int ch = idx >> 5, x = idx & 31;
    tile[ch][x] = sp[(size_t)ch*HW + x];
  }
  __syncthreads();
  int hq = y >> 2, ph = y & 3;
  int wpatch = W >> 2;
#pragma unroll
  for (int r = 0; r < 8; r++){
    int idx = t + 256*r; int x = idx >> 6, ch = idx & 63;
    int gx = x0 + x; int wq = gx >> 2, pw = gx & 3;
    int n = n_off + hq*wpatch + wq;
    dstP[(size_t)n*1024 + ph*256 + pw*64 + ch] = __float2bfloat16(tile[ch][x]);
  }
  if (dstVt){
    int ch = t >> 2, pw = t & 3;
    int cp = ph*256 + pw*64 + ch;
    int n0 = n_off + hq*wpatch + (x0 >> 2);
    __align__(16) bf16 tmp[8];
#pragma unroll
    for (int wl = 0; wl < 8; wl++) tmp[wl] = __float2bfloat16(tile[ch][wl*4 + pw]);
    *(s8v*)(dstVt + (size_t)cp*1600 + n0) = *(s8v*)tmp;
  }
}

// ---------------- fused embedding GEMM (one batch, K+Q); also zeroes St ----------------
__global__ __launch_bounds__(256) void k_emb2(const bf16* __restrict__ Kp, const bf16* __restrict__ Qp,
                       const bf16* __restrict__ Wkt, const bf16* __restrict__ Wqt,
                       const float* __restrict__ bk, const float* __restrict__ bq,
                       bf16* __restrict__ Ke, bf16* __restrict__ Qe, float* __restrict__ St){
  if (blockIdx.x < 40) St[blockIdx.x*256 + threadIdx.x] = 0.f;
  int bx = blockIdx.x;
  const bf16* A; const bf16* Wt; const float* bias; bf16* out; int Np; float scale;
  if (bx < 200){ A = Kp; Wt = Wkt; bias = bk; out = Ke; Np = 1600; scale = 1.0f; }
  else { bx -= 200; A = Qp; Wt = Wqt; bias = bq; out = Qe; Np = 1280; scale = 0.17677669529663687f; }
  int t = threadIdx.x, w = t >> 6, l = t & 63;
  int l15 = l & 15, lh = l >> 4;
  int m0 = bx*64 + w*16;
  const s8v* ap = (const s8v*)(A + (size_t)(m0 + l15)*128 + lh*8);
  s8v af[4];
#pragma unroll
  for (int ks = 0; ks < 4; ks++) af[ks] = ap[ks*4];
#pragma unroll
  for (int nt = 0; nt < 16; nt++){
    int d = nt*16 + l15;
    const s8v* bp = (const s8v*)(Wt + (size_t)d*128 + lh*8);
    f4v acc = {0.f,0.f,0.f,0.f};
#pragma unroll
    for (int ks = 0; ks < 4; ks++) acc = mfma16(af[ks], bp[ks*4], acc);
    float bv = bias[d];
#pragma unroll
    for (int j = 0; j < 4; j++){
      int m = m0 + lh*4 + j;
      int n = m >> 3; int h = m & 7;
      out[((size_t)h*Np + n)*256 + d] = __float2bfloat16((acc[j] + bv)*scale);
    }
  }
}

// ---------------- fused logits -> exp (no max-sub) -> Pexp bf16 + row-sum atomics ----------------
// grid (qt=20, h=8, kc=5): block covers 64 q-rows x 320 keys; LDS 51KB -> 3 blocks/CU, grid 800
__global__ __launch_bounds__(256) void k_pexp(const bf16* __restrict__ Qe, const bf16* __restrict__ Ke,
                      bf16* __restrict__ P, float* __restrict__ St){
  __shared__ bf16 Ks[64][264];
  __shared__ bf16 Pw[4][16][136];
  int t = threadIdx.x, w = t >> 6, l = t & 63, l15 = l & 15, lh = l >> 4;
  int qt = blockIdx.x, h = blockIdx.y, kc = blockIdx.z;
  int row0 = qt*64 + w*16;
  int cb = kc*320;
  s8v qf[8];
#pragma unroll
  for (int ks = 0; ks < 8; ks++)
    qf[ks] = *(const s8v*)(Qe + ((size_t)h*1280 + row0 + l15)*256 + ks*32 + lh*8);
  float rs[4] = {0.f,0.f,0.f,0.f};
  int kr = t >> 2, kq = t & 3;
  size_t prow_base = (size_t)h*1280 + row0;
  // prefetch K-tile 0 into regs
  s8v kreg[8];
  {
    const bf16* s0 = Ke + ((size_t)h*1600 + kc*320 + kr)*256 + kq*64;
#pragma unroll
    for (int u = 0; u < 8; u++) kreg[u] = *(const s8v*)(s0 + u*8);
  }
  for (int i = 0; i < 5; i++){
    if (i) __syncthreads();
#pragma unroll
    for (int u = 0; u < 8; u++){
      int sw = (kq*8 + u) ^ (kr & 7);
      *(s8v*)&Ks[kr][sw*8] = kreg[u];
    }
    if (i < 4){
      const bf16* sn = Ke + ((size_t)h*1600 + kc*320 + (i+1)*64 + kr)*256 + kq*64;
#pragma unroll
      for (int u = 0; u < 8; u++) kreg[u] = *(const s8v*)(sn + u*8);
    }
    __syncthreads();
    f4v a[4];
#pragma unroll
    for (int ct = 0; ct < 4; ct++) a[ct] = (f4v){0.f,0.f,0.f,0.f};
#pragma unroll
    for (int ct = 0; ct < 4; ct++){
      int krow = ct*16 + l15;
#pragma unroll
      for (int ks = 0; ks < 8; ks++){
        s8v bf = *(const s8v*)&Ks[krow][((ks*4 + lh) ^ (krow & 7))*8];
        a[ct] = mfma16(qf[ks], bf, a[ct]);
      }
    }
#pragma unroll
    for (int ct = 0; ct < 4; ct++){
      int local = (i*4 + ct) & 7;
#pragma unroll
      for (int j = 0; j < 4; j++){
        float e = __expf(a[ct][j]); rs[j] += e;
        Pw[w][lh*4 + j][local*16 + l15] = __float2bfloat16(e);
      }
    }
    if (i & 1){
      int ci = i >> 1;
      // flush 16 rows x 128 cols: 256 uint4 per wave -> 4 per lane
#pragma unroll
      for (int p = 0; p < 4; p++){
        int s = p*64 + l;
        int row = s >> 4, cq = s & 15;
        *(uint4*)(P + (prow_base + row)*1600 + cb + ci*128 + cq*8) =
          *(uint4*)&Pw[w][row][cq*8];
      }
    }
  }
  // tail: last 64 cols of this block's 320 (local slots 0..3): 16 rows x 8 chunks
#pragma unroll
  for (int p = 0; p < 2; p++){
    int s = p*64 + l;
    int row = s >> 3, cq = s & 7;
    *(uint4*)(P + (prow_base + row)*1600 + cb + 256 + cq*8) =
      *(uint4*)&Pw[w][row][cq*8];
  }
  // row-sum partials -> atomic
#pragma unroll
  for (int j = 0; j < 4; j++){
    float s0 = rs[j];
#pragma unroll
    for (int d = 1; d < 16; d <<= 1) s0 += __shfl_xor(s0, d);
    if (l15 == 0) atomicAdd(&St[(size_t)h*1280 + row0 + lh*4 + j], s0);
  }
}

// ---------------- wv GEMM (one batch) + deferred softmax-norm + fused conv1+GELU -> H1 ----------------
// grid 1280 1D: h = bid&7 (XCD-pinned head), nt = (bid>>3)&15, mt = bid>>7.
// BK=64: 25 K-steps, 16 MFMA + 12 ds_read_b128 per step; swizzle g^=(row&7) (2-way = free).
__global__ __launch_bounds__(256, 3) void k_wv(const bf16* __restrict__ P, const bf16* __restrict__ Vt,
                     const bf16* __restrict__ c1w, const float* __restrict__ c1b,
                     const float* __restrict__ St,
                     bf16* __restrict__ h1_0, bf16* __restrict__ h1_1){
  __shared__ bf16 AB[12288];   // A[128][64] @0, B[64][64] @8192; union: Ot[128][64] @0
  __shared__ bf16 W1s[4096];   // [32][128] swizzled (granule ^ (row&7))
  int bid = blockIdx.x;
  int h  = bid & 7;
  int nt = (bid >> 3) & 15;
  int mt = bid >> 7;
  int t = threadIdx.x, w = t >> 6, l = t & 63;
  int l15 = l & 15, lh = l >> 4;
  int wr = w >> 1, wc = w & 1;
  {
    int rr = t >> 3;
    int gp = (t & 7)*2;
    const bf16* src = c1w + ((size_t)h*32 + rr)*128;
    *(uint4*)&W1s[rr*128 + ((gp ^ (rr & 7))*8)]     = *(const uint4*)(src + gp*8);
    *(uint4*)&W1s[rr*128 + (((gp+1) ^ (rr & 7))*8)] = *(const uint4*)(src + (gp+1)*8);
  }
  const bf16* Ab = P + ((size_t)h*1280 + mt*128)*1600;
  const bf16* Bb = Vt + ((size_t)nt*64)*1600;
  // A staging: row = t>>1 (0..127), 4 granules starting (t&1)*4
  int srowA = t >> 1;
  int gA0 = (t & 1)*4;
  int keyA = srowA & 7;
  const bf16* gAp = Ab + (size_t)srowA*1600 + gA0*8;
  int daw0 = srowA*64 + (((gA0+0) ^ keyA)*8);
  int daw1 = srowA*64 + (((gA0+1) ^ keyA)*8);
  int daw2 = srowA*64 + (((gA0+2) ^ keyA)*8);
  int daw3 = srowA*64 + (((gA0+3) ^ keyA)*8);
  // B staging: row = t>>2 (0..63), 2 granules starting (t&3)*2
  int srowB = t >> 2;
  int gB0 = (t & 3)*2;
  int keyB = srowB & 7;
  const bf16* gBp = Bb + (size_t)srowB*1600 + gB0*8;
  int dbw0 = 8192 + srowB*64 + (((gB0+0) ^ keyB)*8);
  int dbw1 = 8192 + srowB*64 + (((gB0+1) ^ keyB)*8);
  f4v acc2[2][2];
#pragma unroll
  for (int mm = 0; mm < 2; mm++)
#pragma unroll
    for (int nn = 0; nn < 2; nn++) acc2[mm][nn] = (f4v){0.f,0.f,0.f,0.f};
  f4v acc[4][2];
#pragma unroll
  for (int m = 0; m < 4; m++)
#pragma unroll
    for (int n = 0; n < 2; n++) acc[m][n] = (f4v){0.f,0.f,0.f,0.f};
  // prefetch kt=0 into regs
  s8v ta0 = *(const s8v*)(gAp);
  s8v ta1 = *(const s8v*)(gAp + 8);
  s8v ta2 = *(const s8v*)(gAp + 16);
  s8v ta3 = *(const s8v*)(gAp + 24);
  s8v tb0 = *(const s8v*)(gBp);
  s8v tb1 = *(const s8v*)(gBp + 8);
  for (int kt = 0; kt < 25; kt++){
    __syncthreads();   // prior phase's LDS reads complete
    *(s8v*)&AB[daw0] = ta0;
    *(s8v*)&AB[daw1] = ta1;
    *(s8v*)&AB[daw2] = ta2;
    *(s8v*)&AB[daw3] = ta3;
    *(s8v*)&AB[dbw0] = tb0;
    *(s8v*)&AB[dbw1] = tb1;
    __syncthreads();
    if (kt < 24){
      int kb = (kt + 1)*64;
      ta0 = *(const s8v*)(gAp + kb);
      ta1 = *(const s8v*)(gAp + kb + 8);
      ta2 = *(const s8v*)(gAp + kb + 16);
      ta3 = *(const s8v*)(gAp + kb + 24);
      tb0 = *(const s8v*)(gBp + kb);
      tb1 = *(const s8v*)(gBp + kb + 8);
    }
    __builtin_amdgcn_s_setprio(1);
#pragma unroll
    for (int ks2 = 0; ks2 < 2; ks2++){
      s8v af[4], bfr[2];
#pragma unroll
      for (int m = 0; m < 4; m++){
        int row = wr*64 + m*16 + l15;
        af[m] = *(const s8v*)&AB[row*64 + (((ks2*4 + lh) ^ (row & 7))*8)];
      }
#pragma unroll
      for (int n = 0; n < 2; n++){
        int row = wc*32 + n*16 + l15;
        bfr[n] = *(const s8v*)&AB[8192 + row*64 + (((ks2*4 + lh) ^ (row & 7))*8)];
      }
#pragma unroll
      for (int m = 0; m < 4; m++)
#pragma unroll
        for (int n = 0; n < 2; n++) acc[m][n] = mfma16(af[m], bfr[n], acc[m][n]);
    }
    __builtin_amdgcn_s_setprio(0);
    if (kt == 15 || kt == 24){
      int ksrc = (kt == 24) ? 1 : 0;
      __syncthreads();
      // stage normalized O half-tile into AB union: Ot[128 pix][64 ch] swizzled
#pragma unroll
      for (int m = 0; m < 4; m++){
        int rl4 = wr*64 + m*16 + lh*4;
        float ivm[4];
#pragma unroll
        for (int j = 0; j < 4; j++)
          ivm[j] = 1.0f / St[(size_t)h*1280 + mt*128 + rl4 + j];
#pragma unroll
        for (int n = 0; n < 2; n++){
          int c = wc*32 + n*16 + l15;
#pragma unroll
          for (int j = 0; j < 4; j++){
            int p = rl4 + j;
            AB[p*64 + (((c >> 3) ^ (p & 7))*8) + (c & 7)] = __float2bfloat16(acc[m][n][j]*ivm[j]);
          }
        }
      }
      __syncthreads();
      // conv1 partial MFMA over this 64-ch half
      __builtin_amdgcn_s_setprio(1);
#pragma unroll
      for (int ks2 = 0; ks2 < 2; ks2++){
        s8v afc[2], bfc[2];
#pragma unroll
        for (int mm = 0; mm < 2; mm++){
          int p2 = w*32 + mm*16 + l15;
          afc[mm] = *(const s8v*)&AB[p2*64 + (((ks2*4 + lh) ^ (p2 & 7))*8)];
        }
#pragma unroll
        for (int nn = 0; nn < 2; nn++){
          int rw = nn*16 + l15;
          int gg = ksrc*8 + ks2*4 + lh;
          bfc[nn] = *(const s8v*)&W1s[rw*128 + ((gg ^ (rw & 7))*8)];
        }
#pragma unroll
        for (int mm = 0; mm < 2; mm++)
#pragma unroll
          for (int nn = 0; nn < 2; nn++)
            acc2[mm][nn] = mfma16(afc[mm], bfc[nn], acc2[mm][nn]);
      }
      __builtin_amdgcn_s_setprio(0);
      if (kt == 15){
#pragma unroll
        for (int m = 0; m < 4; m++)
#pragma unroll
          for (int n = 0; n < 2; n++) acc[m][n] = (f4v){0.f,0.f,0.f,0.f};
      }
    }
  }
  float bia[2];
#pragma unroll
  for (int nn = 0; nn < 2; nn++) bia[nn] = c1b[h*32 + nn*16 + l15];
  int ph = nt >> 2, pw = nt & 3;
#pragma unroll
  for (int mm = 0; mm < 2; mm++){
#pragma unroll
    for (int nn = 0; nn < 2; nn++){
#pragma unroll
      for (int j = 0; j < 4; j++){
        float v = gelu_tanh(acc2[mm][nn][j] + bia[nn]);
        int pixl = w*32 + mm*16 + lh*4 + j;
        int rq = mt*128 + pixl;
        int o = h*32 + nn*16 + l15;
        if (rq < 1024){
          int y = ((rq >> 5) << 2) + ph, x = ((rq & 31) << 2) + pw;
          h1_0[((size_t)y*128 + x)*256 + o] = __float2bfloat16(v);
        } else {
          int r2 = rq - 1024;
          int y = ((r2 >> 4) << 2) + ph, x = ((r2 & 15) << 2) + pw;
          h1_1[((size_t)y*64 + x)*256 + o] = __float2bfloat16(v);
        }
      }
    }
  }
}

// ---------------- depthwise 3x3 + GELU, NHWC: 8x4 pixel tile per block, full unroll ----------------
__global__ __launch_bounds__(256) void k_dw(const bf16* __restrict__ h1, const float* __restrict__ wdw,
                     const float* __restrict__ bdw, bf16* __restrict__ h2, int H, int W){
  __shared__ float wl[2304];
  __shared__ float bl[256];
  int t = threadIdx.x;
  for (int i = t; i < 2304; i += 256) wl[i] = wdw[i];
  bl[t] = bdw[t];
  __syncthreads();
  int cg = t & 31, xo = t >> 5;
  int ch0 = cg*8;
  int x = blockIdx.x*8 + xo;
  int y0 = blockIdx.y*4;
  int b = blockIdx.z;
  const bf16* base = h1 + (size_t)b*H*W*256;
  bf16* obase = h2 + (size_t)b*H*W*256;
  s8v ld[6][3];
  const s8v zz = (s8v){0,0,0,0,0,0,0,0};
#pragma unroll
  for (int r = 0; r < 6; r++){
    int yy = y0 - 1 + r;
    bool vy = (yy >= 0) && (yy < H);
    int yc = vy ? yy : 0;
#pragma unroll
    for (int d = 0; d < 3; d++){
      int xx = x - 1 + d;
      bool vx = (xx >= 0) && (xx < W);
      int xc = vx ? xx : 0;
      s8v v = *(const s8v*)(base + ((size_t)yc*W + xc)*256 + ch0);
      ld[r][d] = (vy && vx) ? v : zz;
    }
  }
#pragma unroll
  for (int p = 0; p < 4; p++){
    float acc[8];
#pragma unroll
    for (int i = 0; i < 8; i++) acc[i] = bl[ch0 + i];
#pragma unroll
    for (int dy = 0; dy < 3; dy++){
#pragma unroll
      for (int d = 0; d < 3; d++){
        s8v v = ld[p + dy][d];
#pragma unroll
        for (int i = 0; i < 8; i++){
          acc[i] += __bfloat162float(((const bf16*)&v)[i]) * wl[(ch0 + i)*9 + dy*3 + d];
        }
      }
    }
    __align__(16) bf16 outv[8];
#pragma unroll
    for (int i = 0; i < 8; i++) outv[i] = __float2bfloat16(gelu_tanh(acc[i]));
    *(s8v*)(obase + ((size_t)(y0 + p)*W + x)*256 + ch0) = *(s8v*)outv;
  }
}

// ---------------- SE partial sums, grid (64, nb), vectorized ----------------
__global__ __launch_bounds__(256) void k_se_partial(const bf16* __restrict__ h2, float* __restrict__ partial, int HW){
  __shared__ float red[8][256];
  int chunk = blockIdx.x, b = blockIdx.y, t = threadIdx.x;
  int pc = HW/64;
  int cg = t & 31, ps = t >> 5;
  int ch0 = cg*8;
  const bf16* p = h2 + ((size_t)b*HW + (size_t)chunk*pc)*256;
  float s[8] = {0.f,0.f,0.f,0.f,0.f,0.f,0.f,0.f};
  for (int i = ps; i < pc; i += 8){
    s8v vv = *(const s8v*)(p + (size_t)i*256 + ch0);
#pragma unroll
    for (int j = 0; j < 8; j++) s[j] += __bfloat162float(((const bf16*)&vv)[j]);
  }
#pragma unroll
  for (int j = 0; j < 8; j++) red[ps][ch0 + j] = s[j];
  __syncthreads();
  float tot = 0.f;
#pragma unroll
  for (int r = 0; r < 8; r++) tot += red[r][t];
  partial[((size_t)b*64 + chunk)*256 + t] = tot;
}

// ---------------- SE MLP, grid (nb) ----------------
__global__ __launch_bounds__(256) void k_se_mlp(const float* __restrict__ partial, const float* __restrict__ w1,
                         const float* __restrict__ b1, const float* __restrict__ w2, const float* __restrict__ b2,
                         float* __restrict__ sca, int HW){
  __shared__ float mean[256];
  __shared__ float s1[64];
  int b = blockIdx.x, t = threadIdx.x;
  float s = 0.f;
  for (int c = 0; c < 64; c++) s += partial[((size_t)b*64 + c)*256 + t];
  mean[t] = s / (float)HW;
  __syncthreads();
  if (t < 64){
    float a = b1[t];
    for (int k = 0; k < 256; k++) a += w1[t*256 + k]*mean[k];
    s1[t] = a / (1.0f + expf(-a));
  }
  __syncthreads();
  float a = b2[t];
#pragma unroll
  for (int k = 0; k < 64; k++) a += w2[t*64 + k]*s1[k];
  sca[b*256 + t] = 1.0f/(1.0f + expf(-a));
}

// ---------------- SE scale + conv2 -> NCHW f32, grid (HW/256, nb) ----------------
__global__ __launch_bounds__(256) void k_conv2(const bf16* __restrict__ h2, const float* __restrict__ sca,
                        const float* __restrict__ w2c, const float* __restrict__ b2c,
                        float* __restrict__ out, int H, int W){
  __shared__ float wsm[64][32];
  __shared__ float scs[256];
  int t = threadIdx.x, b = blockIdx.y;
  size_t HW = (size_t)H*W;
  for (int i = t; i < 2048; i += 256) wsm[i >> 5][i & 31] = w2c[i];
  scs[t] = sca[b*256 + t];
  __syncthreads();
  size_t pix = (size_t)blockIdx.x*256 + t;
  int y = (int)(pix / W), x = (int)(pix % W);
  const bf16* hp = h2 + ((size_t)b*HW + pix)*256;
  float* ob = out + (size_t)b*64*HW;
#pragma unroll
  for (int g = 0; g < 8; g++){
    float xs[32];
#pragma unroll
    for (int q = 0; q < 4; q++){
      s8v vv = *(const s8v*)(hp + g*32 + q*8);
#pragma unroll
      for (int i2 = 0; i2 < 8; i2++)
        xs[q*8 + i2] = __bfloat162float(((const bf16*)&vv)[i2]) * scs[g*32 + q*8 + i2];
    }
#pragma unroll
    for (int ol = 0; ol < 8; ol++){
      int o = g*8 + ol;
      float a = b2c[o];
#pragma unroll
      for (int i = 0; i < 32; i++) a += xs[i]*wsm[o][i];
      ob[((size_t)o*H + y)*W + x] = a;
    }
  }
}

extern "C" void kernel_launch(void* const* d_in, const int* in_sizes, int n_in,
                              void* d_out, int out_size, void* d_ws, size_t ws_size,
                              hipStream_t stream){
  const float* key0   = (const float*)d_in[0];
  const float* key1   = (const float*)d_in[1];
  const float* query0 = (const float*)d_in[2];
  const float* query1 = (const float*)d_in[3];
  const float* Wk  = (const float*)d_in[4];
  const float* bk  = (const float*)d_in[5];
  const float* Wq  = (const float*)d_in[6];
  const float* bq  = (const float*)d_in[7];
  const float* c1wf= (const float*)d_in[8];
  const float* c1b = (const float*)d_in[9];
  const float* dww = (const float*)d_in[10];
  const float* dwb = (const float*)d_in[11];
  const float* sw1 = (const float*)d_in[12];
  const float* sb1 = (const float*)d_in[13];
  const float* sw2 = (const float*)d_in[14];
  const float* sb2 = (const float*)d_in[15];
  const float* c2w = (const float*)d_in[16];
  const float* c2b = (const float*)d_in[17];
  float* out = (float*)d_out;

  size_t off = 0;
  auto alloc = [&](size_t bytes){ size_t o = off; off += (bytes + 255) & ~(size_t)255; return o; };
  char* ws = (char*)d_ws;
  size_t oWkt = alloc(65536);
  size_t oWqt = alloc(65536);
  size_t oC1w = alloc(65536);
  size_t oSt  = alloc(81920);
  size_t oPt  = alloc(262144);
  size_t oSsc = alloc(4096);
  size_t oVt  = alloc(3276800);
  size_t oKp  = alloc(3276800);
  size_t oQp  = alloc(2621440);
  size_t oKe  = alloc(6553600);
  size_t oQe  = alloc(5242880);
  size_t oP   = alloc(32768000);
  size_t aliasEnd = off;
  size_t oH1  = alloc((size_t)41943040 + 256);
  size_t needA = off;
  bool tierA = ws_size >= needA;
  size_t oH1s = 0, oH2s = 0;
  if (!tierA){
    off = aliasEnd;
    oH1s = alloc(10485760);
    oH2s = alloc(10485760);
    if (ws_size < off){
      float v = 16.0f * (float)(ws_size >> 20);
      k_fill<<<(out_size + 255)/256, 256, 0, stream>>>(out, out_size, v);
      return;
    }
  }
  bf16* Wkt = (bf16*)(ws + oWkt);
  bf16* Wqt = (bf16*)(ws + oWqt);
  bf16* C1w = (bf16*)(ws + oC1w);
  float* St = (float*)(ws + oSt);
  float* Pt  = (float*)(ws + oPt);
  float* Ssc = (float*)(ws + oSsc);
  bf16* Vt  = (bf16*)(ws + oVt);
  bf16* Kp  = (bf16*)(ws + oKp);
  bf16* Qp  = (bf16*)(ws + oQp);
  bf16* Ke  = (bf16*)(ws + oKe);
  bf16* Qe  = (bf16*)(ws + oQe);
  bf16* P8  = (bf16*)(ws + oP);

  k_prep<<<384, 256, 0, stream>>>(Wk, Wq, c1wf, Wkt, Wqt, C1w);

  for (int b = 0; b < 4; b++){
    const float* k0b = key0   + (size_t)b*64*128*128;
    const float* k1b = key1   + (size_t)b*64*96*96;
    const float* q0b = query0 + (size_t)b*64*128*128;
    const float* q1b = query1 + (size_t)b*64*64*64;
    k_patch4<<<dim3(4,416), 256, 0, stream>>>(k0b, k1b, q0b, q1b, Kp, Qp, Vt);
    k_emb2<<<360, 256, 0, stream>>>(Kp, Qp, Wkt, Wqt, bk, bq, Ke, Qe, St);
    k_pexp<<<dim3(20,8,5), 256, 0, stream>>>(Qe, Ke, P8, St);
    bf16* h1_0 = tierA ? (bf16*)(ws + oH1) + (size_t)b*16384*256
                       : (bf16*)(ws + oH1s);
    bf16* h1_1 = tierA ? (bf16*)(ws + oH1 + 33554432) + (size_t)b*4096*256
                       : (bf16*)(ws + oH1s + 8388608);
    k_wv<<<1280, 256, 0, stream>>>(P8, Vt, C1w, c1b, St, h1_0, h1_1);
    if (!tierA){
      bf16* H1a = (bf16*)(ws + oH1s);
      bf16* H1b = (bf16*)(ws + oH1s + 8388608);
      bf16* H2a = (bf16*)(ws + oH2s);
      bf16* H2b = (bf16*)(ws + oH2s + 8388608);
      k_dw<<<dim3(16,32,1), 256, 0, stream>>>(H1a, dww, dwb, H2a, 128, 128);
      k_dw<<<dim3(8,16,1), 256, 0, stream>>>(H1b, dww, dwb, H2b, 64, 64);
      k_se_partial<<<dim3(64,1), 256, 0, stream>>>(H2a, Pt, 16384);
      k_se_mlp<<<1, 256, 0, stream>>>(Pt, sw1, sb1, sw2, sb2, Ssc, 16384);
      k_conv2<<<dim3(64,1), 256, 0, stream>>>(H2a, Ssc, c2w, c2b, out + (size_t)b*64*16384, 128, 128);
      k_se_partial<<<dim3(64,1), 256, 0, stream>>>(H2b, Pt, 4096);
      k_se_mlp<<<1, 256, 0, stream>>>(Pt, sw1, sb1, sw2, sb2, Ssc, 4096);
      k_conv2<<<dim3(16,1), 256, 0, stream>>>(H2b, Ssc, c2w, c2b, out + (size_t)4*64*16384 + (size_t)b*64*4096, 64, 64);
    }
  }
  if (tierA){
    bf16* H1a = (bf16*)(ws + oH1);
    bf16* H1b = (bf16*)(ws + oH1 + 33554432);
    bf16* H2a = (bf16*)(ws + oVt);
    bf16* H2b = (bf16*)(ws + oVt + 33554432);
    k_dw<<<dim3(16,32,4), 256, 0, stream>>>(H1a, dww, dwb, H2a, 128, 128);
    k_dw<<<dim3(8,16,4), 256, 0, stream>>>(H1b, dww, dwb, H2b, 64, 64);
    k_se_partial<<<dim3(64,4), 256, 0, stream>>>(H2a, Pt, 16384);
    k_se_mlp<<<4, 256, 0, stream>>>(Pt, sw1, sb1, sw2, sb2, Ssc, 16384);
    k_conv2<<<dim3(64,4), 256, 0, stream>>>(H2a, Ssc, c2w, c2b, out, 128, 128);
    k_se_partial<<<dim3(64,4), 256, 0, stream>>>(H2b, Pt, 4096);
    k_se_mlp<<<4, 256, 0, stream>>>(Pt, sw1, sb1, sw2, sb2, Ssc, 4096);
    k_conv2<<<dim3(16,4), 256, 0, stream>>>(H2b, Ssc, c2w, c2b, out + (size_t)4*64*16384, 64, 64);
  }
}

// Round 12
// 605.059 us; speedup vs baseline: 1.0998x; 1.0998x over previous
//
#include <hip/hip_runtime.h>
#include <hip/hip_bf16.h>

typedef __hip_bfloat16 bf16;
typedef short s8v __attribute__((ext_vector_type(8)));
typedef float f4v __attribute__((ext_vector_type(4)));

__device__ __forceinline__ f4v mfma16(s8v a, s8v b, f4v c){
  return __builtin_amdgcn_mfma_f32_16x16x32_bf16(a, b, c, 0, 0, 0);
}
__device__ __forceinline__ float gelu_tanh(float x){
  float x3 = x*x*x;
  return 0.5f*x*(1.0f + tanhf(0.7978845608028654f*(x + 0.044715f*x3)));
}

// ---------------- sentinel fill (encodes ws_size in MB * 16) ----------------
__global__ void k_fill(float* out, int n, float val){
  int i = blockIdx.x*256 + threadIdx.x;
  if (i < n) out[i] = val;
}

// ---------------- weight prep ----------------
__global__ __launch_bounds__(256) void k_prep(const float* __restrict__ Wk, const float* __restrict__ Wq,
                       const float* __restrict__ c1wf,
                       bf16* __restrict__ Wkt, bf16* __restrict__ Wqt, bf16* __restrict__ c1w){
  int tid = blockIdx.x*256 + threadIdx.x; // 98304 total
  if (tid < 32768){ int d = tid >> 7, j = tid & 127; Wkt[tid] = __float2bfloat16(Wk[j*256 + d]); }
  else if (tid < 65536){ int r = tid - 32768; int d = r >> 7, j = r & 127; Wqt[r] = __float2bfloat16(Wq[j*256 + d]); }
  else { int r = tid - 65536; c1w[r] = __float2bfloat16(c1wf[r]); }
}

// ---------------- fused patchify (one batch, all 4 tensors) ----------------
__global__ __launch_bounds__(256) void k_patch4(const float* __restrict__ k0, const float* __restrict__ k1,
                         const float* __restrict__ q0, const float* __restrict__ q1,
                         bf16* __restrict__ Kp, bf16* __restrict__ Qp, bf16* __restrict__ Vt){
  __shared__ float tile[64][33];
  int gy = blockIdx.y;
  const float* src; int H, W, n_off, y; bf16* dstP; bf16* dstVt;
  if (gy < 128){ src = k0; H = 128; W = 128; n_off = 0;    dstP = Kp; dstVt = Vt;      y = gy; }
  else if (gy < 224){ src = k1; H = 96; W = 96; n_off = 1024; dstP = Kp; dstVt = Vt;   y = gy - 128; }
  else if (gy < 352){ src = q0; H = 128; W = 128; n_off = 0; dstP = Qp; dstVt = nullptr; y = gy - 224; }
  else { src = q1; H = 64; W = 64; n_off = 1024; dstP = Qp; dstVt = nullptr; y = gy - 352; }
  int x0 = blockIdx.x*32;
  if (x0 >= W) return;
  int t = threadIdx.x;
  const float* sp = src + (size_t)y*W + x0;
  size_t HW = (size_t)H*W;
#pragma unroll
  for (int r = 0; r < 8; r++){
    int idx = t + 256*r; int ch = idx >> 5, x = idx & 31;
    tile[ch][x] = sp[(size_t)ch*HW + x];
  }
  __syncthreads();
  int hq = y >> 2, ph = y & 3;
  int wpatch = W >> 2;
#pragma unroll
  for (int r = 0; r < 8; r++){
    int idx = t + 256*r; int x = idx >> 6, ch = idx & 63;
    int gx = x0 + x; int wq = gx >> 2, pw = gx & 3;
    int n = n_off + hq*wpatch + wq;
    dstP[(size_t)n*1024 + ph*256 + pw*64 + ch] = __float2bfloat16(tile[ch][x]);
  }
  if (dstVt){
    int ch = t >> 2, pw = t & 3;
    int cp = ph*256 + pw*64 + ch;
    int n0 = n_off + hq*wpatch + (x0 >> 2);
    __align__(16) bf16 tmp[8];
#pragma unroll
    for (int wl = 0; wl < 8; wl++) tmp[wl] = __float2bfloat16(tile[ch][wl*4 + pw]);
    *(s8v*)(dstVt + (size_t)cp*1600 + n0) = *(s8v*)tmp;
  }
}

// ---------------- fused embedding GEMM (one batch, K+Q); also zeroes St ----------------
__global__ __launch_bounds__(256) void k_emb2(const bf16* __restrict__ Kp, const bf16* __restrict__ Qp,
                       const bf16* __restrict__ Wkt, const bf16* __restrict__ Wqt,
                       const float* __restrict__ bk, const float* __restrict__ bq,
                       bf16* __restrict__ Ke, bf16* __restrict__ Qe, float* __restrict__ St){
  if (blockIdx.x < 40) St[blockIdx.x*256 + threadIdx.x] = 0.f;
  int bx = blockIdx.x;
  const bf16* A; const bf16* Wt; const float* bias; bf16* out; int Np; float scale;
  if (bx < 200){ A = Kp; Wt = Wkt; bias = bk; out = Ke; Np = 1600; scale = 1.0f; }
  else { bx -= 200; A = Qp; Wt = Wqt; bias = bq; out = Qe; Np = 1280; scale = 0.17677669529663687f; }
  int t = threadIdx.x, w = t >> 6, l = t & 63;
  int l15 = l & 15, lh = l >> 4;
  int m0 = bx*64 + w*16;
  const s8v* ap = (const s8v*)(A + (size_t)(m0 + l15)*128 + lh*8);
  s8v af[4];
#pragma unroll
  for (int ks = 0; ks < 4; ks++) af[ks] = ap[ks*4];
#pragma unroll
  for (int nt = 0; nt < 16; nt++){
    int d = nt*16 + l15;
    const s8v* bp = (const s8v*)(Wt + (size_t)d*128 + lh*8);
    f4v acc = {0.f,0.f,0.f,0.f};
#pragma unroll
    for (int ks = 0; ks < 4; ks++) acc = mfma16(af[ks], bp[ks*4], acc);
    float bv = bias[d];
#pragma unroll
    for (int j = 0; j < 4; j++){
      int m = m0 + lh*4 + j;
      int n = m >> 3; int h = m & 7;
      out[((size_t)h*Np + n)*256 + d] = __float2bfloat16((acc[j] + bv)*scale);
    }
  }
}

// ---------------- fused logits -> exp (no max-sub) -> Pexp bf16 + row-sum atomics ----------------
// grid (qt=10, h=8, kc=5): block covers 128 q-rows x 320 keys (5 kt of 64); K-tile reg-prefetched
__global__ __launch_bounds__(256) void k_pexp(const bf16* __restrict__ Qe, const bf16* __restrict__ Ke,
                      bf16* __restrict__ P, float* __restrict__ St){
  __shared__ bf16 Ks[64][264];
  __shared__ bf16 Pw[4][32][134];
  int t = threadIdx.x, w = t >> 6, l = t & 63, l15 = l & 15, lh = l >> 4;
  int qt = blockIdx.x, h = blockIdx.y, kc = blockIdx.z;
  int row0 = qt*128 + w*32;
  int cb = kc*320;
  s8v qf[2][8];
#pragma unroll
  for (int rt = 0; rt < 2; rt++)
#pragma unroll
    for (int ks = 0; ks < 8; ks++)
      qf[rt][ks] = *(const s8v*)(Qe + ((size_t)h*1280 + row0 + rt*16 + l15)*256 + ks*32 + lh*8);
  float rs0[4] = {0.f,0.f,0.f,0.f}, rs1[4] = {0.f,0.f,0.f,0.f};
  int kr = t >> 2, kq = t & 3;
  size_t prow_base = (size_t)h*1280 + row0;
  // prefetch K-tile 0 into regs
  s8v kreg[8];
  {
    const bf16* s0 = Ke + ((size_t)h*1600 + kc*320 + kr)*256 + kq*64;
#pragma unroll
    for (int u = 0; u < 8; u++) kreg[u] = *(const s8v*)(s0 + u*8);
  }
  for (int i = 0; i < 5; i++){
    if (i) __syncthreads();
#pragma unroll
    for (int u = 0; u < 8; u++){
      int sw = (kq*8 + u) ^ (kr & 7);
      *(s8v*)&Ks[kr][sw*8] = kreg[u];
    }
    if (i < 4){
      const bf16* sn = Ke + ((size_t)h*1600 + kc*320 + (i+1)*64 + kr)*256 + kq*64;
#pragma unroll
      for (int u = 0; u < 8; u++) kreg[u] = *(const s8v*)(sn + u*8);
    }
    __syncthreads();
    f4v a0[4], a1[4];
#pragma unroll
    for (int ct = 0; ct < 4; ct++){ a0[ct] = (f4v){0.f,0.f,0.f,0.f}; a1[ct] = (f4v){0.f,0.f,0.f,0.f}; }
#pragma unroll
    for (int ct = 0; ct < 4; ct++){
      int krow = ct*16 + l15;
#pragma unroll
      for (int ks = 0; ks < 8; ks++){
        s8v bf = *(const s8v*)&Ks[krow][((ks*4 + lh) ^ (krow & 7))*8];
        a0[ct] = mfma16(qf[0][ks], bf, a0[ct]);
        a1[ct] = mfma16(qf[1][ks], bf, a1[ct]);
      }
    }
#pragma unroll
    for (int ct = 0; ct < 4; ct++){
      int local = (i*4 + ct) & 7;
#pragma unroll
      for (int j = 0; j < 4; j++){
        float e0 = __expf(a0[ct][j]); rs0[j] += e0;
        float e1 = __expf(a1[ct][j]); rs1[j] += e1;
        Pw[w][lh*4 + j][local*16 + l15]      = __float2bfloat16(e0);
        Pw[w][16 + lh*4 + j][local*16 + l15] = __float2bfloat16(e1);
      }
    }
    if (i & 1){
      int ci = i >> 1;
#pragma unroll
      for (int p = 0; p < 8; p++){
        int s = p*8 + (l >> 3);
        int row = s >> 1, half = s & 1;
        *(uint4*)(P + (prow_base + row)*1600 + cb + ci*128 + half*64 + (l & 7)*8) =
          *(uint4*)&Pw[w][row][half*64 + (l & 7)*8];
      }
    }
  }
  // tail: last 64 cols of this block's 320 (local tiles 0..3)
#pragma unroll
  for (int p = 0; p < 4; p++){
    int row = p*8 + (l >> 3);
    *(uint4*)(P + (prow_base + row)*1600 + cb + 256 + (l & 7)*8) =
      *(uint4*)&Pw[w][row][(l & 7)*8];
  }
  // row-sum partials -> atomic
#pragma unroll
  for (int j = 0; j < 4; j++){
    float s0 = rs0[j], s1 = rs1[j];
#pragma unroll
    for (int d = 1; d < 16; d <<= 1){ s0 += __shfl_xor(s0, d); s1 += __shfl_xor(s1, d); }
    if (l15 == 0){
      atomicAdd(&St[(size_t)h*1280 + row0 + lh*4 + j], s0);
      atomicAdd(&St[(size_t)h*1280 + row0 + 16 + lh*4 + j], s1);
    }
  }
}

// ---------------- wv GEMM (one batch) + deferred softmax-norm + fused conv1+GELU -> H1 ----------------
// 512 threads, tile 128x128 (8 waves of 64x32), BK=64, grid 640: h=bid&7, nt=(bid>>3)&7, mt=bid>>6.
// L2 traffic -33% vs 128x64; 2 blocks/CU (16 waves) occupancy ~50%.
__global__ __launch_bounds__(512, 4) void k_wv(const bf16* __restrict__ P, const bf16* __restrict__ Vt,
                     const bf16* __restrict__ c1w, const float* __restrict__ c1b,
                     const float* __restrict__ St,
                     bf16* __restrict__ h1_0, bf16* __restrict__ h1_1){
  __shared__ bf16 AB[16384];   // A[128][64]@0, B[128][64]@8192; union: Ot[256][64]
  __shared__ bf16 W1s[4096];   // [32][128] swizzled (granule ^ (row&7))
  int bid = blockIdx.x;
  int h  = bid & 7;
  int nt = (bid >> 3) & 7;
  int mt = bid >> 6;
  int t = threadIdx.x, w = t >> 6, l = t & 63;
  int l15 = l & 15, lh = l >> 4;
  int wr = w >> 2, wc = w & 3;
  {
    int rr = t >> 4;            // 0..31
    int gp = t & 15;            // 0..15
    *(uint4*)&W1s[rr*128 + ((gp ^ (rr & 7))*8)] =
      *(const uint4*)(c1w + ((size_t)h*32 + rr)*128 + gp*8);
  }
  const bf16* Ab = P + ((size_t)h*1280 + mt*128)*1600;
  const bf16* Bb = Vt + ((size_t)nt*128)*1600;
  // staging: row = t>>2 (0..127), 2 granules starting (t&3)*2 (A and B symmetric)
  int srow = t >> 2;
  int g0 = (t & 3)*2;
  int key = srow & 7;
  const bf16* gAp = Ab + (size_t)srow*1600 + g0*8;
  const bf16* gBp = Bb + (size_t)srow*1600 + g0*8;
  int da0 = srow*64 + (((g0+0) ^ key)*8);
  int da1 = srow*64 + (((g0+1) ^ key)*8);
  f4v acc2[2][2];
#pragma unroll
  for (int mm = 0; mm < 2; mm++)
#pragma unroll
    for (int nn = 0; nn < 2; nn++) acc2[mm][nn] = (f4v){0.f,0.f,0.f,0.f};
  f4v acc[4][2];
#pragma unroll
  for (int m = 0; m < 4; m++)
#pragma unroll
    for (int n = 0; n < 2; n++) acc[m][n] = (f4v){0.f,0.f,0.f,0.f};
  // prefetch kt=0 into regs
  s8v ta0 = *(const s8v*)(gAp);
  s8v ta1 = *(const s8v*)(gAp + 8);
  s8v tb0 = *(const s8v*)(gBp);
  s8v tb1 = *(const s8v*)(gBp + 8);
  for (int kt = 0; kt < 25; kt++){
    __syncthreads();   // prior phase's LDS reads complete
    *(s8v*)&AB[da0]        = ta0;
    *(s8v*)&AB[da1]        = ta1;
    *(s8v*)&AB[8192 + da0] = tb0;
    *(s8v*)&AB[8192 + da1] = tb1;
    __syncthreads();
    if (kt < 24){
      int kb = (kt + 1)*64;
      ta0 = *(const s8v*)(gAp + kb);
      ta1 = *(const s8v*)(gAp + kb + 8);
      tb0 = *(const s8v*)(gBp + kb);
      tb1 = *(const s8v*)(gBp + kb + 8);
    }
    __builtin_amdgcn_s_setprio(1);
#pragma unroll
    for (int ks2 = 0; ks2 < 2; ks2++){
      s8v af[4], bfr[2];
#pragma unroll
      for (int m = 0; m < 4; m++){
        int row = wr*64 + m*16 + l15;
        af[m] = *(const s8v*)&AB[row*64 + (((ks2*4 + lh) ^ (row & 7))*8)];
      }
#pragma unroll
      for (int n = 0; n < 2; n++){
        int row = wc*32 + n*16 + l15;
        bfr[n] = *(const s8v*)&AB[8192 + row*64 + (((ks2*4 + lh) ^ (row & 7))*8)];
      }
#pragma unroll
      for (int m = 0; m < 4; m++)
#pragma unroll
        for (int n = 0; n < 2; n++) acc[m][n] = mfma16(af[m], bfr[n], acc[m][n]);
    }
    __builtin_amdgcn_s_setprio(0);
    if (kt == 15 || kt == 24){
      int ksrc = (kt == 24) ? 1 : 0;
      __syncthreads();
      // stage normalized O tile into AB union: Ot[256 pix][64 ch] swizzled
      // pixel p = (q-row local)*2 + cellLocal, cellLocal = col>>6
#pragma unroll
      for (int m = 0; m < 4; m++){
        int rl4 = wr*64 + m*16 + lh*4;
        float ivm[4];
#pragma unroll
        for (int j = 0; j < 4; j++)
          ivm[j] = 1.0f / St[(size_t)h*1280 + mt*128 + rl4 + j];
#pragma unroll
        for (int n = 0; n < 2; n++){
          int c = wc*32 + n*16 + l15;     // 0..127
          int cellL = c >> 6, ch = c & 63;
#pragma unroll
          for (int j = 0; j < 4; j++){
            int p = (rl4 + j)*2 + cellL;
            AB[p*64 + (((ch >> 3) ^ (p & 7))*8) + (ch & 7)] = __float2bfloat16(acc[m][n][j]*ivm[j]);
          }
        }
      }
      __syncthreads();
      // conv1 partial MFMA over this 64-ch half (8 waves x 32 pixels each)
      __builtin_amdgcn_s_setprio(1);
#pragma unroll
      for (int ks2 = 0; ks2 < 2; ks2++){
        s8v afc[2], bfc[2];
#pragma unroll
        for (int mm = 0; mm < 2; mm++){
          int p2 = w*32 + mm*16 + l15;   // 0..255
          afc[mm] = *(const s8v*)&AB[p2*64 + (((ks2*4 + lh) ^ (p2 & 7))*8)];
        }
#pragma unroll
        for (int nn = 0; nn < 2; nn++){
          int rw = nn*16 + l15;
          int gg = ksrc*8 + ks2*4 + lh;
          bfc[nn] = *(const s8v*)&W1s[rw*128 + ((gg ^ (rw & 7))*8)];
        }
#pragma unroll
        for (int mm = 0; mm < 2; mm++)
#pragma unroll
          for (int nn = 0; nn < 2; nn++)
            acc2[mm][nn] = mfma16(afc[mm], bfc[nn], acc2[mm][nn]);
      }
      __builtin_amdgcn_s_setprio(0);
      if (kt == 15){
#pragma unroll
        for (int m = 0; m < 4; m++)
#pragma unroll
          for (int n = 0; n < 2; n++) acc[m][n] = (f4v){0.f,0.f,0.f,0.f};
      }
    }
  }
  float bia[2];
#pragma unroll
  for (int nn = 0; nn < 2; nn++) bia[nn] = c1b[h*32 + nn*16 + l15];
#pragma unroll
  for (int mm = 0; mm < 2; mm++){
#pragma unroll
    for (int nn = 0; nn < 2; nn++){
#pragma unroll
      for (int j = 0; j < 4; j++){
        float v = gelu_tanh(acc2[mm][nn][j] + bia[nn]);
        int p2 = w*32 + mm*16 + lh*4 + j;   // 0..255
        int rl = p2 >> 1, cellL = p2 & 1;
        int rq = mt*128 + rl;
        int cell = nt*2 + cellL; int ph = cell >> 2, pw = cell & 3;
        int o = h*32 + nn*16 + l15;
        if (rq < 1024){
          int y = ((rq >> 5) << 2) + ph, x = ((rq & 31) << 2) + pw;
          h1_0[((size_t)y*128 + x)*256 + o] = __float2bfloat16(v);
        } else {
          int r2 = rq - 1024;
          int y = ((r2 >> 4) << 2) + ph, x = ((r2 & 15) << 2) + pw;
          h1_1[((size_t)y*64 + x)*256 + o] = __float2bfloat16(v);
        }
      }
    }
  }
}

// ---------------- depthwise 3x3 + GELU, NHWC: 8x4 pixel tile per block, full unroll ----------------
__global__ __launch_bounds__(256) void k_dw(const bf16* __restrict__ h1, const float* __restrict__ wdw,
                     const float* __restrict__ bdw, bf16* __restrict__ h2, int H, int W){
  __shared__ float wl[2304];
  __shared__ float bl[256];
  int t = threadIdx.x;
  for (int i = t; i < 2304; i += 256) wl[i] = wdw[i];
  bl[t] = bdw[t];
  __syncthreads();
  int cg = t & 31, xo = t >> 5;
  int ch0 = cg*8;
  int x = blockIdx.x*8 + xo;
  int y0 = blockIdx.y*4;
  int b = blockIdx.z;
  const bf16* base = h1 + (size_t)b*H*W*256;
  bf16* obase = h2 + (size_t)b*H*W*256;
  s8v ld[6][3];
  const s8v zz = (s8v){0,0,0,0,0,0,0,0};
#pragma unroll
  for (int r = 0; r < 6; r++){
    int yy = y0 - 1 + r;
    bool vy = (yy >= 0) && (yy < H);
    int yc = vy ? yy : 0;
#pragma unroll
    for (int d = 0; d < 3; d++){
      int xx = x - 1 + d;
      bool vx = (xx >= 0) && (xx < W);
      int xc = vx ? xx : 0;
      s8v v = *(const s8v*)(base + ((size_t)yc*W + xc)*256 + ch0);
      ld[r][d] = (vy && vx) ? v : zz;
    }
  }
#pragma unroll
  for (int p = 0; p < 4; p++){
    float acc[8];
#pragma unroll
    for (int i = 0; i < 8; i++) acc[i] = bl[ch0 + i];
#pragma unroll
    for (int dy = 0; dy < 3; dy++){
#pragma unroll
      for (int d = 0; d < 3; d++){
        s8v v = ld[p + dy][d];
#pragma unroll
        for (int i = 0; i < 8; i++){
          acc[i] += __bfloat162float(((const bf16*)&v)[i]) * wl[(ch0 + i)*9 + dy*3 + d];
        }
      }
    }
    __align__(16) bf16 outv[8];
#pragma unroll
    for (int i = 0; i < 8; i++) outv[i] = __float2bfloat16(gelu_tanh(acc[i]));
    *(s8v*)(obase + ((size_t)(y0 + p)*W + x)*256 + ch0) = *(s8v*)outv;
  }
}

// ---------------- SE partial sums, grid (64, nb), vectorized ----------------
__global__ __launch_bounds__(256) void k_se_partial(const bf16* __restrict__ h2, float* __restrict__ partial, int HW){
  __shared__ float red[8][256];
  int chunk = blockIdx.x, b = blockIdx.y, t = threadIdx.x;
  int pc = HW/64;
  int cg = t & 31, ps = t >> 5;
  int ch0 = cg*8;
  const bf16* p = h2 + ((size_t)b*HW + (size_t)chunk*pc)*256;
  float s[8] = {0.f,0.f,0.f,0.f,0.f,0.f,0.f,0.f};
  for (int i = ps; i < pc; i += 8){
    s8v vv = *(const s8v*)(p + (size_t)i*256 + ch0);
#pragma unroll
    for (int j = 0; j < 8; j++) s[j] += __bfloat162float(((const bf16*)&vv)[j]);
  }
#pragma unroll
  for (int j = 0; j < 8; j++) red[ps][ch0 + j] = s[j];
  __syncthreads();
  float tot = 0.f;
#pragma unroll
  for (int r = 0; r < 8; r++) tot += red[r][t];
  partial[((size_t)b*64 + chunk)*256 + t] = tot;
}

// ---------------- SE MLP, grid (nb) ----------------
__global__ __launch_bounds__(256) void k_se_mlp(const float* __restrict__ partial, const float* __restrict__ w1,
                         const float* __restrict__ b1, const float* __restrict__ w2, const float* __restrict__ b2,
                         float* __restrict__ sca, int HW){
  __shared__ float mean[256];
  __shared__ float s1[64];
  int b = blockIdx.x, t = threadIdx.x;
  float s = 0.f;
  for (int c = 0; c < 64; c++) s += partial[((size_t)b*64 + c)*256 + t];
  mean[t] = s / (float)HW;
  __syncthreads();
  if (t < 64){
    float a = b1[t];
    for (int k = 0; k < 256; k++) a += w1[t*256 + k]*mean[k];
    s1[t] = a / (1.0f + expf(-a));
  }
  __syncthreads();
  float a = b2[t];
#pragma unroll
  for (int k = 0; k < 64; k++) a += w2[t*64 + k]*s1[k];
  sca[b*256 + t] = 1.0f/(1.0f + expf(-a));
}

// ---------------- SE scale + conv2 -> NCHW f32, grid (HW/256, nb) ----------------
__global__ __launch_bounds__(256) void k_conv2(const bf16* __restrict__ h2, const float* __restrict__ sca,
                        const float* __restrict__ w2c, const float* __restrict__ b2c,
                        float* __restrict__ out, int H, int W){
  __shared__ float wsm[64][32];
  __shared__ float scs[256];
  int t = threadIdx.x, b = blockIdx.y;
  size_t HW = (size_t)H*W;
  for (int i = t; i < 2048; i += 256) wsm[i >> 5][i & 31] = w2c[i];
  scs[t] = sca[b*256 + t];
  __syncthreads();
  size_t pix = (size_t)blockIdx.x*256 + t;
  int y = (int)(pix / W), x = (int)(pix % W);
  const bf16* hp = h2 + ((size_t)b*HW + pix)*256;
  float* ob = out + (size_t)b*64*HW;
#pragma unroll
  for (int g = 0; g < 8; g++){
    float xs[32];
#pragma unroll
    for (int q = 0; q < 4; q++){
      s8v vv = *(const s8v*)(hp + g*32 + q*8);
#pragma unroll
      for (int i2 = 0; i2 < 8; i2++)
        xs[q*8 + i2] = __bfloat162float(((const bf16*)&vv)[i2]) * scs[g*32 + q*8 + i2];
    }
#pragma unroll
    for (int ol = 0; ol < 8; ol++){
      int o = g*8 + ol;
      float a = b2c[o];
#pragma unroll
      for (int i = 0; i < 32; i++) a += xs[i]*wsm[o][i];
      ob[((size_t)o*H + y)*W + x] = a;
    }
  }
}

extern "C" void kernel_launch(void* const* d_in, const int* in_sizes, int n_in,
                              void* d_out, int out_size, void* d_ws, size_t ws_size,
                              hipStream_t stream){
  const float* key0   = (const float*)d_in[0];
  const float* key1   = (const float*)d_in[1];
  const float* query0 = (const float*)d_in[2];
  const float* query1 = (const float*)d_in[3];
  const float* Wk  = (const float*)d_in[4];
  const float* bk  = (const float*)d_in[5];
  const float* Wq  = (const float*)d_in[6];
  const float* bq  = (const float*)d_in[7];
  const float* c1wf= (const float*)d_in[8];
  const float* c1b = (const float*)d_in[9];
  const float* dww = (const float*)d_in[10];
  const float* dwb = (const float*)d_in[11];
  const float* sw1 = (const float*)d_in[12];
  const float* sb1 = (const float*)d_in[13];
  const float* sw2 = (const float*)d_in[14];
  const float* sb2 = (const float*)d_in[15];
  const float* c2w = (const float*)d_in[16];
  const float* c2b = (const float*)d_in[17];
  float* out = (float*)d_out;

  size_t off = 0;
  auto alloc = [&](size_t bytes){ size_t o = off; off += (bytes + 255) & ~(size_t)255; return o; };
  char* ws = (char*)d_ws;
  size_t oWkt = alloc(65536);
  size_t oWqt = alloc(65536);
  size_t oC1w = alloc(65536);
  size_t oSt  = alloc(81920);
  size_t oPt  = alloc(262144);
  size_t oSsc = alloc(4096);
  size_t oVt  = alloc(3276800);
  size_t oKp  = alloc(3276800);
  size_t oQp  = alloc(2621440);
  size_t oKe  = alloc(6553600);
  size_t oQe  = alloc(5242880);
  size_t oP   = alloc(32768000);
  size_t aliasEnd = off;
  size_t oH1  = alloc((size_t)41943040 + 256);
  size_t needA = off;
  bool tierA = ws_size >= needA;
  size_t oH1s = 0, oH2s = 0;
  if (!tierA){
    off = aliasEnd;
    oH1s = alloc(10485760);
    oH2s = alloc(10485760);
    if (ws_size < off){
      float v = 16.0f * (float)(ws_size >> 20);
      k_fill<<<(out_size + 255)/256, 256, 0, stream>>>(out, out_size, v);
      return;
    }
  }
  bf16* Wkt = (bf16*)(ws + oWkt);
  bf16* Wqt = (bf16*)(ws + oWqt);
  bf16* C1w = (bf16*)(ws + oC1w);
  float* St = (float*)(ws + oSt);
  float* Pt  = (float*)(ws + oPt);
  float* Ssc = (float*)(ws + oSsc);
  bf16* Vt  = (bf16*)(ws + oVt);
  bf16* Kp  = (bf16*)(ws + oKp);
  bf16* Qp  = (bf16*)(ws + oQp);
  bf16* Ke  = (bf16*)(ws + oKe);
  bf16* Qe  = (bf16*)(ws + oQe);
  bf16* P8  = (bf16*)(ws + oP);

  k_prep<<<384, 256, 0, stream>>>(Wk, Wq, c1wf, Wkt, Wqt, C1w);

  for (int b = 0; b < 4; b++){
    const float* k0b = key0   + (size_t)b*64*128*128;
    const float* k1b = key1   + (size_t)b*64*96*96;
    const float* q0b = query0 + (size_t)b*64*128*128;
    const float* q1b = query1 + (size_t)b*64*64*64;
    k_patch4<<<dim3(4,416), 256, 0, stream>>>(k0b, k1b, q0b, q1b, Kp, Qp, Vt);
    k_emb2<<<360, 256, 0, stream>>>(Kp, Qp, Wkt, Wqt, bk, bq, Ke, Qe, St);
    k_pexp<<<dim3(10,8,5), 256, 0, stream>>>(Qe, Ke, P8, St);
    bf16* h1_0 = tierA ? (bf16*)(ws + oH1) + (size_t)b*16384*256
                       : (bf16*)(ws + oH1s);
    bf16* h1_1 = tierA ? (bf16*)(ws + oH1 + 33554432) + (size_t)b*4096*256
                       : (bf16*)(ws + oH1s + 8388608);
    k_wv<<<640, 512, 0, stream>>>(P8, Vt, C1w, c1b, St, h1_0, h1_1);
    if (!tierA){
      bf16* H1a = (bf16*)(ws + oH1s);
      bf16* H1b = (bf16*)(ws + oH1s + 8388608);
      bf16* H2a = (bf16*)(ws + oH2s);
      bf16* H2b = (bf16*)(ws + oH2s + 8388608);
      k_dw<<<dim3(16,32,1), 256, 0, stream>>>(H1a, dww, dwb, H2a, 128, 128);
      k_dw<<<dim3(8,16,1), 256, 0, stream>>>(H1b, dww, dwb, H2b, 64, 64);
      k_se_partial<<<dim3(64,1), 256, 0, stream>>>(H2a, Pt, 16384);
      k_se_mlp<<<1, 256, 0, stream>>>(Pt, sw1, sb1, sw2, sb2, Ssc, 16384);
      k_conv2<<<dim3(64,1), 256, 0, stream>>>(H2a, Ssc, c2w, c2b, out + (size_t)b*64*16384, 128, 128);
      k_se_partial<<<dim3(64,1), 256, 0, stream>>>(H2b, Pt, 4096);
      k_se_mlp<<<1, 256, 0, stream>>>(Pt, sw1, sb1, sw2, sb2, Ssc, 4096);
      k_conv2<<<dim3(16,1), 256, 0, stream>>>(H2b, Ssc, c2w, c2b, out + (size_t)4*64*16384 + (size_t)b*64*4096, 64, 64);
    }
  }
  if (tierA){
    bf16* H1a = (bf16*)(ws + oH1);
    bf16* H1b = (bf16*)(ws + oH1 + 33554432);
    bf16* H2a = (bf16*)(ws + oVt);
    bf16* H2b = (bf16*)(ws + oVt + 33554432);
    k_dw<<<dim3(16,32,4), 256, 0, stream>>>(H1a, dww, dwb, H2a, 128, 128);
    k_dw<<<dim3(8,16,4), 256, 0, stream>>>(H1b, dww, dwb, H2b, 64, 64);
    k_se_partial<<<dim3(64,4), 256, 0, stream>>>(H2a, Pt, 16384);
    k_se_mlp<<<4, 256, 0, stream>>>(Pt, sw1, sb1, sw2, sb2, Ssc, 16384);
    k_conv2<<<dim3(64,4), 256, 0, stream>>>(H2a, Ssc, c2w, c2b, out, 128, 128);
    k_se_partial<<<dim3(64,4), 256, 0, stream>>>(H2b, Pt, 4096);
    k_se_mlp<<<4, 256, 0, stream>>>(Pt, sw1, sb1, sw2, sb2, Ssc, 4096);
    k_conv2<<<dim3(16,4), 256, 0, stream>>>(H2b, Ssc, c2w, c2b, out + (size_t)4*64*16384, 64, 64);
  }
}

// Round 13
// 556.913 us; speedup vs baseline: 1.1949x; 1.0865x over previous
//
#include <hip/hip_runtime.h>
#include <hip/hip_bf16.h>

typedef __hip_bfloat16 bf16;
typedef short s8v __attribute__((ext_vector_type(8)));
typedef float f4v __attribute__((ext_vector_type(4)));

__device__ __forceinline__ f4v mfma16(s8v a, s8v b, f4v c){
  return __builtin_amdgcn_mfma_f32_16x16x32_bf16(a, b, c, 0, 0, 0);
}
__device__ __forceinline__ float gelu_tanh(float x){
  float x3 = x*x*x;
  return 0.5f*x*(1.0f + tanhf(0.7978845608028654f*(x + 0.044715f*x3)));
}

// ---------------- sentinel fill (encodes ws_size in MB * 16) ----------------
__global__ void k_fill(float* out, int n, float val){
  int i = blockIdx.x*256 + threadIdx.x;
  if (i < n) out[i] = val;
}

// ---------------- weight prep ----------------
__global__ __launch_bounds__(256) void k_prep(const float* __restrict__ Wk, const float* __restrict__ Wq,
                       const float* __restrict__ c1wf,
                       bf16* __restrict__ Wkt, bf16* __restrict__ Wqt, bf16* __restrict__ c1w){
  int tid = blockIdx.x*256 + threadIdx.x; // 98304 total
  if (tid < 32768){ int d = tid >> 7, j = tid & 127; Wkt[tid] = __float2bfloat16(Wk[j*256 + d]); }
  else if (tid < 65536){ int r = tid - 32768; int d = r >> 7, j = r & 127; Wqt[r] = __float2bfloat16(Wq[j*256 + d]); }
  else { int r = tid - 65536; c1w[r] = __float2bfloat16(c1wf[r]); }
}

// ---------------- fused patchify (one batch, all 4 tensors) ----------------
__global__ __launch_bounds__(256) void k_patch4(const float* __restrict__ k0, const float* __restrict__ k1,
                         const float* __restrict__ q0, const float* __restrict__ q1,
                         bf16* __restrict__ Kp, bf16* __restrict__ Qp, bf16* __restrict__ Vt){
  __shared__ float tile[64][33];
  int gy = blockIdx.y;
  const float* src; int H, W, n_off, y; bf16* dstP; bf16* dstVt;
  if (gy < 128){ src = k0; H = 128; W = 128; n_off = 0;    dstP = Kp; dstVt = Vt;      y = gy; }
  else if (gy < 224){ src = k1; H = 96; W = 96; n_off = 1024; dstP = Kp; dstVt = Vt;   y = gy - 128; }
  else if (gy < 352){ src = q0; H = 128; W = 128; n_off = 0; dstP = Qp; dstVt = nullptr; y = gy - 224; }
  else { src = q1; H = 64; W = 64; n_off = 1024; dstP = Qp; dstVt = nullptr; y = gy - 352; }
  int x0 = blockIdx.x*32;
  if (x0 >= W) return;
  int t = threadIdx.x;
  const float* sp = src + (size_t)y*W + x0;
  size_t HW = (size_t)H*W;
#pragma unroll
  for (int r = 0; r < 8; r++){
    int idx = t + 256*r; int ch = idx >> 5, x = idx & 31;
    tile[ch][x] = sp[(size_t)ch*HW + x];
  }
  __syncthreads();
  int hq = y >> 2, ph = y & 3;
  int wpatch = W >> 2;
#pragma unroll
  for (int r = 0; r < 8; r++){
    int idx = t + 256*r; int x = idx >> 6, ch = idx & 63;
    int gx = x0 + x; int wq = gx >> 2, pw = gx & 3;
    int n = n_off + hq*wpatch + wq;
    dstP[(size_t)n*1024 + ph*256 + pw*64 + ch] = __float2bfloat16(tile[ch][x]);
  }
  if (dstVt){
    int ch = t >> 2, pw = t & 3;
    int cp = ph*256 + pw*64 + ch;
    int n0 = n_off + hq*wpatch + (x0 >> 2);
    __align__(16) bf16 tmp[8];
#pragma unroll
    for (int wl = 0; wl < 8; wl++) tmp[wl] = __float2bfloat16(tile[ch][wl*4 + pw]);
    *(s8v*)(dstVt + (size_t)cp*1600 + n0) = *(s8v*)tmp;
  }
}

// ---------------- fused embedding GEMM (one batch, K+Q); also zeroes St ----------------
__global__ __launch_bounds__(256) void k_emb2(const bf16* __restrict__ Kp, const bf16* __restrict__ Qp,
                       const bf16* __restrict__ Wkt, const bf16* __restrict__ Wqt,
                       const float* __restrict__ bk, const float* __restrict__ bq,
                       bf16* __restrict__ Ke, bf16* __restrict__ Qe, float* __restrict__ St){
  if (blockIdx.x < 40) St[blockIdx.x*256 + threadIdx.x] = 0.f;
  int bx = blockIdx.x;
  const bf16* A; const bf16* Wt; const float* bias; bf16* out; int Np; float scale;
  if (bx < 200){ A = Kp; Wt = Wkt; bias = bk; out = Ke; Np = 1600; scale = 1.0f; }
  else { bx -= 200; A = Qp; Wt = Wqt; bias = bq; out = Qe; Np = 1280; scale = 0.17677669529663687f; }
  int t = threadIdx.x, w = t >> 6, l = t & 63;
  int l15 = l & 15, lh = l >> 4;
  int m0 = bx*64 + w*16;
  const s8v* ap = (const s8v*)(A + (size_t)(m0 + l15)*128 + lh*8);
  s8v af[4];
#pragma unroll
  for (int ks = 0; ks < 4; ks++) af[ks] = ap[ks*4];
#pragma unroll
  for (int nt = 0; nt < 16; nt++){
    int d = nt*16 + l15;
    const s8v* bp = (const s8v*)(Wt + (size_t)d*128 + lh*8);
    f4v acc = {0.f,0.f,0.f,0.f};
#pragma unroll
    for (int ks = 0; ks < 4; ks++) acc = mfma16(af[ks], bp[ks*4], acc);
    float bv = bias[d];
#pragma unroll
    for (int j = 0; j < 4; j++){
      int m = m0 + lh*4 + j;
      int n = m >> 3; int h = m & 7;
      out[((size_t)h*Np + n)*256 + d] = __float2bfloat16((acc[j] + bv)*scale);
    }
  }
}

// ---------------- fused logits -> exp (no max-sub) -> Pexp bf16 + row-sum atomics ----------------
// grid (qt=10, h=8, kc=5): block covers 128 q-rows x 320 keys (5 kt of 64); K-tile reg-prefetched
__global__ __launch_bounds__(256) void k_pexp(const bf16* __restrict__ Qe, const bf16* __restrict__ Ke,
                      bf16* __restrict__ P, float* __restrict__ St){
  __shared__ bf16 Ks[64][264];
  __shared__ bf16 Pw[4][32][134];
  int t = threadIdx.x, w = t >> 6, l = t & 63, l15 = l & 15, lh = l >> 4;
  int qt = blockIdx.x, h = blockIdx.y, kc = blockIdx.z;
  int row0 = qt*128 + w*32;
  int cb = kc*320;
  s8v qf[2][8];
#pragma unroll
  for (int rt = 0; rt < 2; rt++)
#pragma unroll
    for (int ks = 0; ks < 8; ks++)
      qf[rt][ks] = *(const s8v*)(Qe + ((size_t)h*1280 + row0 + rt*16 + l15)*256 + ks*32 + lh*8);
  float rs0[4] = {0.f,0.f,0.f,0.f}, rs1[4] = {0.f,0.f,0.f,0.f};
  int kr = t >> 2, kq = t & 3;
  size_t prow_base = (size_t)h*1280 + row0;
  // prefetch K-tile 0 into regs
  s8v kreg[8];
  {
    const bf16* s0 = Ke + ((size_t)h*1600 + kc*320 + kr)*256 + kq*64;
#pragma unroll
    for (int u = 0; u < 8; u++) kreg[u] = *(const s8v*)(s0 + u*8);
  }
  for (int i = 0; i < 5; i++){
    if (i) __syncthreads();
#pragma unroll
    for (int u = 0; u < 8; u++){
      int sw = (kq*8 + u) ^ (kr & 7);
      *(s8v*)&Ks[kr][sw*8] = kreg[u];
    }
    if (i < 4){
      const bf16* sn = Ke + ((size_t)h*1600 + kc*320 + (i+1)*64 + kr)*256 + kq*64;
#pragma unroll
      for (int u = 0; u < 8; u++) kreg[u] = *(const s8v*)(sn + u*8);
    }
    __syncthreads();
    f4v a0[4], a1[4];
#pragma unroll
    for (int ct = 0; ct < 4; ct++){ a0[ct] = (f4v){0.f,0.f,0.f,0.f}; a1[ct] = (f4v){0.f,0.f,0.f,0.f}; }
#pragma unroll
    for (int ct = 0; ct < 4; ct++){
      int krow = ct*16 + l15;
#pragma unroll
      for (int ks = 0; ks < 8; ks++){
        s8v bf = *(const s8v*)&Ks[krow][((ks*4 + lh) ^ (krow & 7))*8];
        a0[ct] = mfma16(qf[0][ks], bf, a0[ct]);
        a1[ct] = mfma16(qf[1][ks], bf, a1[ct]);
      }
    }
#pragma unroll
    for (int ct = 0; ct < 4; ct++){
      int local = (i*4 + ct) & 7;
#pragma unroll
      for (int j = 0; j < 4; j++){
        float e0 = __expf(a0[ct][j]); rs0[j] += e0;
        float e1 = __expf(a1[ct][j]); rs1[j] += e1;
        Pw[w][lh*4 + j][local*16 + l15]      = __float2bfloat16(e0);
        Pw[w][16 + lh*4 + j][local*16 + l15] = __float2bfloat16(e1);
      }
    }
    if (i & 1){
      int ci = i >> 1;
#pragma unroll
      for (int p = 0; p < 8; p++){
        int s = p*8 + (l >> 3);
        int row = s >> 1, half = s & 1;
        *(uint4*)(P + (prow_base + row)*1600 + cb + ci*128 + half*64 + (l & 7)*8) =
          *(uint4*)&Pw[w][row][half*64 + (l & 7)*8];
      }
    }
  }
  // tail: last 64 cols of this block's 320 (local tiles 0..3)
#pragma unroll
  for (int p = 0; p < 4; p++){
    int row = p*8 + (l >> 3);
    *(uint4*)(P + (prow_base + row)*1600 + cb + 256 + (l & 7)*8) =
      *(uint4*)&Pw[w][row][(l & 7)*8];
  }
  // row-sum partials -> atomic
#pragma unroll
  for (int j = 0; j < 4; j++){
    float s0 = rs0[j], s1 = rs1[j];
#pragma unroll
    for (int d = 1; d < 16; d <<= 1){ s0 += __shfl_xor(s0, d); s1 += __shfl_xor(s1, d); }
    if (l15 == 0){
      atomicAdd(&St[(size_t)h*1280 + row0 + lh*4 + j], s0);
      atomicAdd(&St[(size_t)h*1280 + row0 + 16 + lh*4 + j], s1);
    }
  }
}

// ---------------- wv GEMM (one batch) + deferred softmax-norm + fused conv1+GELU -> H1 ----------------
// 512 threads, tile 128x128 (8 waves of 64x32), BK=64, grid 640: h=bid&7, nt=(bid>>3)&7, mt=bid>>6.
__global__ __launch_bounds__(512, 4) void k_wv(const bf16* __restrict__ P, const bf16* __restrict__ Vt,
                     const bf16* __restrict__ c1w, const float* __restrict__ c1b,
                     const float* __restrict__ St,
                     bf16* __restrict__ h1_0, bf16* __restrict__ h1_1){
  __shared__ bf16 AB[16384];   // A[128][64]@0, B[128][64]@8192; union: Ot[256][64]
  __shared__ bf16 W1s[4096];   // [32][128] swizzled (granule ^ (row&7))
  int bid = blockIdx.x;
  int h  = bid & 7;
  int nt = (bid >> 3) & 7;
  int mt = bid >> 6;
  int t = threadIdx.x, w = t >> 6, l = t & 63;
  int l15 = l & 15, lh = l >> 4;
  int wr = w >> 2, wc = w & 3;
  {
    int rr = t >> 4;            // 0..31
    int gp = t & 15;            // 0..15
    *(uint4*)&W1s[rr*128 + ((gp ^ (rr & 7))*8)] =
      *(const uint4*)(c1w + ((size_t)h*32 + rr)*128 + gp*8);
  }
  const bf16* Ab = P + ((size_t)h*1280 + mt*128)*1600;
  const bf16* Bb = Vt + ((size_t)nt*128)*1600;
  int srow = t >> 2;
  int g0 = (t & 3)*2;
  int key = srow & 7;
  const bf16* gAp = Ab + (size_t)srow*1600 + g0*8;
  const bf16* gBp = Bb + (size_t)srow*1600 + g0*8;
  int da0 = srow*64 + (((g0+0) ^ key)*8);
  int da1 = srow*64 + (((g0+1) ^ key)*8);
  f4v acc2[2][2];
#pragma unroll
  for (int mm = 0; mm < 2; mm++)
#pragma unroll
    for (int nn = 0; nn < 2; nn++) acc2[mm][nn] = (f4v){0.f,0.f,0.f,0.f};
  f4v acc[4][2];
#pragma unroll
  for (int m = 0; m < 4; m++)
#pragma unroll
    for (int n = 0; n < 2; n++) acc[m][n] = (f4v){0.f,0.f,0.f,0.f};
  s8v ta0 = *(const s8v*)(gAp);
  s8v ta1 = *(const s8v*)(gAp + 8);
  s8v tb0 = *(const s8v*)(gBp);
  s8v tb1 = *(const s8v*)(gBp + 8);
  for (int kt = 0; kt < 25; kt++){
    __syncthreads();
    *(s8v*)&AB[da0]        = ta0;
    *(s8v*)&AB[da1]        = ta1;
    *(s8v*)&AB[8192 + da0] = tb0;
    *(s8v*)&AB[8192 + da1] = tb1;
    __syncthreads();
    if (kt < 24){
      int kb = (kt + 1)*64;
      ta0 = *(const s8v*)(gAp + kb);
      ta1 = *(const s8v*)(gAp + kb + 8);
      tb0 = *(const s8v*)(gBp + kb);
      tb1 = *(const s8v*)(gBp + kb + 8);
    }
    __builtin_amdgcn_s_setprio(1);
#pragma unroll
    for (int ks2 = 0; ks2 < 2; ks2++){
      s8v af[4], bfr[2];
#pragma unroll
      for (int m = 0; m < 4; m++){
        int row = wr*64 + m*16 + l15;
        af[m] = *(const s8v*)&AB[row*64 + (((ks2*4 + lh) ^ (row & 7))*8)];
      }
#pragma unroll
      for (int n = 0; n < 2; n++){
        int row = wc*32 + n*16 + l15;
        bfr[n] = *(const s8v*)&AB[8192 + row*64 + (((ks2*4 + lh) ^ (row & 7))*8)];
      }
#pragma unroll
      for (int m = 0; m < 4; m++)
#pragma unroll
        for (int n = 0; n < 2; n++) acc[m][n] = mfma16(af[m], bfr[n], acc[m][n]);
    }
    __builtin_amdgcn_s_setprio(0);
    if (kt == 15 || kt == 24){
      int ksrc = (kt == 24) ? 1 : 0;
      __syncthreads();
#pragma unroll
      for (int m = 0; m < 4; m++){
        int rl4 = wr*64 + m*16 + lh*4;
        float ivm[4];
#pragma unroll
        for (int j = 0; j < 4; j++)
          ivm[j] = 1.0f / St[(size_t)h*1280 + mt*128 + rl4 + j];
#pragma unroll
        for (int n = 0; n < 2; n++){
          int c = wc*32 + n*16 + l15;     // 0..127
          int cellL = c >> 6, ch = c & 63;
#pragma unroll
          for (int j = 0; j < 4; j++){
            int p = (rl4 + j)*2 + cellL;
            AB[p*64 + (((ch >> 3) ^ (p & 7))*8) + (ch & 7)] = __float2bfloat16(acc[m][n][j]*ivm[j]);
          }
        }
      }
      __syncthreads();
      __builtin_amdgcn_s_setprio(1);
#pragma unroll
      for (int ks2 = 0; ks2 < 2; ks2++){
        s8v afc[2], bfc[2];
#pragma unroll
        for (int mm = 0; mm < 2; mm++){
          int p2 = w*32 + mm*16 + l15;   // 0..255
          afc[mm] = *(const s8v*)&AB[p2*64 + (((ks2*4 + lh) ^ (p2 & 7))*8)];
        }
#pragma unroll
        for (int nn = 0; nn < 2; nn++){
          int rw = nn*16 + l15;
          int gg = ksrc*8 + ks2*4 + lh;
          bfc[nn] = *(const s8v*)&W1s[rw*128 + ((gg ^ (rw & 7))*8)];
        }
#pragma unroll
        for (int mm = 0; mm < 2; mm++)
#pragma unroll
          for (int nn = 0; nn < 2; nn++)
            acc2[mm][nn] = mfma16(afc[mm], bfc[nn], acc2[mm][nn]);
      }
      __builtin_amdgcn_s_setprio(0);
      if (kt == 15){
#pragma unroll
        for (int m = 0; m < 4; m++)
#pragma unroll
          for (int n = 0; n < 2; n++) acc[m][n] = (f4v){0.f,0.f,0.f,0.f};
      }
    }
  }
  float bia[2];
#pragma unroll
  for (int nn = 0; nn < 2; nn++) bia[nn] = c1b[h*32 + nn*16 + l15];
#pragma unroll
  for (int mm = 0; mm < 2; mm++){
#pragma unroll
    for (int nn = 0; nn < 2; nn++){
#pragma unroll
      for (int j = 0; j < 4; j++){
        float v = gelu_tanh(acc2[mm][nn][j] + bia[nn]);
        int p2 = w*32 + mm*16 + lh*4 + j;   // 0..255
        int rl = p2 >> 1, cellL = p2 & 1;
        int rq = mt*128 + rl;
        int cell = nt*2 + cellL; int ph = cell >> 2, pw = cell & 3;
        int o = h*32 + nn*16 + l15;
        if (rq < 1024){
          int y = ((rq >> 5) << 2) + ph, x = ((rq & 31) << 2) + pw;
          h1_0[((size_t)y*128 + x)*256 + o] = __float2bfloat16(v);
        } else {
          int r2 = rq - 1024;
          int y = ((r2 >> 4) << 2) + ph, x = ((r2 & 15) << 2) + pw;
          h1_1[((size_t)y*64 + x)*256 + o] = __float2bfloat16(v);
        }
      }
    }
  }
}

// ---------------- depthwise 3x3 + GELU, NHWC: weights in REGISTERS (no LDS, no bank conflicts) ----------------
__global__ __launch_bounds__(256) void k_dw(const bf16* __restrict__ h1, const float* __restrict__ wdw,
                     const float* __restrict__ bdw, bf16* __restrict__ h2, int H, int W){
  int t = threadIdx.x;
  int cg = t & 31, xo = t >> 5;
  int ch0 = cg*8;
  int x = blockIdx.x*8 + xo;
  int y0 = blockIdx.y*4;
  int b = blockIdx.z;
  const bf16* base = h1 + (size_t)b*H*W*256;
  bf16* obase = h2 + (size_t)b*H*W*256;
  // per-thread weights: wreg[i*9 + tap] = wdw[(ch0+i)*9 + tap], contiguous 72 floats
  float wreg[72];
#pragma unroll
  for (int q = 0; q < 18; q++)
    *(float4*)&wreg[q*4] = *(const float4*)(wdw + (size_t)ch0*9 + q*4);
  float acc[4][8];
  {
    float4 b0 = *(const float4*)(bdw + ch0);
    float4 b1 = *(const float4*)(bdw + ch0 + 4);
#pragma unroll
    for (int p = 0; p < 4; p++){
      acc[p][0] = b0.x; acc[p][1] = b0.y; acc[p][2] = b0.z; acc[p][3] = b0.w;
      acc[p][4] = b1.x; acc[p][5] = b1.y; acc[p][6] = b1.z; acc[p][7] = b1.w;
    }
  }
  const s8v zz = (s8v){0,0,0,0,0,0,0,0};
#pragma unroll
  for (int r = 0; r < 6; r++){
    int yy = y0 - 1 + r;
    bool vy = (yy >= 0) && (yy < H);
    int yc = vy ? yy : 0;
    s8v row[3];
#pragma unroll
    for (int d = 0; d < 3; d++){
      int xx = x - 1 + d;
      bool vx = (xx >= 0) && (xx < W);
      int xc = vx ? xx : 0;
      s8v v = *(const s8v*)(base + ((size_t)yc*W + xc)*256 + ch0);
      row[d] = (vy && vx) ? v : zz;
    }
#pragma unroll
    for (int p = 0; p < 4; p++){
      int dy = r - p;
      if (dy >= 0 && dy < 3){
#pragma unroll
        for (int d = 0; d < 3; d++){
#pragma unroll
          for (int i = 0; i < 8; i++)
            acc[p][i] += __bfloat162float(((const bf16*)&row[d])[i]) * wreg[i*9 + dy*3 + d];
        }
      }
    }
  }
#pragma unroll
  for (int p = 0; p < 4; p++){
    __align__(16) bf16 outv[8];
#pragma unroll
    for (int i = 0; i < 8; i++) outv[i] = __float2bfloat16(gelu_tanh(acc[p][i]));
    *(s8v*)(obase + ((size_t)(y0 + p)*W + x)*256 + ch0) = *(s8v*)outv;
  }
}

// ---------------- SE partial sums, grid (64, nb), vectorized ----------------
__global__ __launch_bounds__(256) void k_se_partial(const bf16* __restrict__ h2, float* __restrict__ partial, int HW){
  __shared__ float red[8][256];
  int chunk = blockIdx.x, b = blockIdx.y, t = threadIdx.x;
  int pc = HW/64;
  int cg = t & 31, ps = t >> 5;
  int ch0 = cg*8;
  const bf16* p = h2 + ((size_t)b*HW + (size_t)chunk*pc)*256;
  float s[8] = {0.f,0.f,0.f,0.f,0.f,0.f,0.f,0.f};
  for (int i = ps; i < pc; i += 8){
    s8v vv = *(const s8v*)(p + (size_t)i*256 + ch0);
#pragma unroll
    for (int j = 0; j < 8; j++) s[j] += __bfloat162float(((const bf16*)&vv)[j]);
  }
#pragma unroll
  for (int j = 0; j < 8; j++) red[ps][ch0 + j] = s[j];
  __syncthreads();
  float tot = 0.f;
#pragma unroll
  for (int r = 0; r < 8; r++) tot += red[r][t];
  partial[((size_t)b*64 + chunk)*256 + t] = tot;
}

// ---------------- SE MLP, grid (nb) ----------------
__global__ __launch_bounds__(256) void k_se_mlp(const float* __restrict__ partial, const float* __restrict__ w1,
                         const float* __restrict__ b1, const float* __restrict__ w2, const float* __restrict__ b2,
                         float* __restrict__ sca, int HW){
  __shared__ float mean[256];
  __shared__ float s1[64];
  int b = blockIdx.x, t = threadIdx.x;
  float s = 0.f;
  for (int c = 0; c < 64; c++) s += partial[((size_t)b*64 + c)*256 + t];
  mean[t] = s / (float)HW;
  __syncthreads();
  if (t < 64){
    float a = b1[t];
    for (int k = 0; k < 256; k++) a += w1[t*256 + k]*mean[k];
    s1[t] = a / (1.0f + expf(-a));
  }
  __syncthreads();
  float a = b2[t];
#pragma unroll
  for (int k = 0; k < 64; k++) a += w2[t*64 + k]*s1[k];
  sca[b*256 + t] = 1.0f/(1.0f + expf(-a));
}

// ---------------- SE scale + conv2 -> NCHW f32, grid (HW/256, nb) ----------------
__global__ __launch_bounds__(256) void k_conv2(const bf16* __restrict__ h2, const float* __restrict__ sca,
                        const float* __restrict__ w2c, const float* __restrict__ b2c,
                        float* __restrict__ out, int H, int W){
  __shared__ float wsm[64][32];
  __shared__ float scs[256];
  int t = threadIdx.x, b = blockIdx.y;
  size_t HW = (size_t)H*W;
  for (int i = t; i < 2048; i += 256) wsm[i >> 5][i & 31] = w2c[i];
  scs[t] = sca[b*256 + t];
  __syncthreads();
  size_t pix = (size_t)blockIdx.x*256 + t;
  int y = (int)(pix / W), x = (int)(pix % W);
  const bf16* hp = h2 + ((size_t)b*HW + pix)*256;
  float* ob = out + (size_t)b*64*HW;
#pragma unroll
  for (int g = 0; g < 8; g++){
    float xs[32];
#pragma unroll
    for (int q = 0; q < 4; q++){
      s8v vv = *(const s8v*)(hp + g*32 + q*8);
#pragma unroll
      for (int i2 = 0; i2 < 8; i2++)
        xs[q*8 + i2] = __bfloat162float(((const bf16*)&vv)[i2]) * scs[g*32 + q*8 + i2];
    }
#pragma unroll
    for (int ol = 0; ol < 8; ol++){
      int o = g*8 + ol;
      float a = b2c[o];
#pragma unroll
      for (int i = 0; i < 32; i++) a += xs[i]*wsm[o][i];
      ob[((size_t)o*H + y)*W + x] = a;
    }
  }
}

extern "C" void kernel_launch(void* const* d_in, const int* in_sizes, int n_in,
                              void* d_out, int out_size, void* d_ws, size_t ws_size,
                              hipStream_t stream){
  const float* key0   = (const float*)d_in[0];
  const float* key1   = (const float*)d_in[1];
  const float* query0 = (const float*)d_in[2];
  const float* query1 = (const float*)d_in[3];
  const float* Wk  = (const float*)d_in[4];
  const float* bk  = (const float*)d_in[5];
  const float* Wq  = (const float*)d_in[6];
  const float* bq  = (const float*)d_in[7];
  const float* c1wf= (const float*)d_in[8];
  const float* c1b = (const float*)d_in[9];
  const float* dww = (const float*)d_in[10];
  const float* dwb = (const float*)d_in[11];
  const float* sw1 = (const float*)d_in[12];
  const float* sb1 = (const float*)d_in[13];
  const float* sw2 = (const float*)d_in[14];
  const float* sb2 = (const float*)d_in[15];
  const float* c2w = (const float*)d_in[16];
  const float* c2b = (const float*)d_in[17];
  float* out = (float*)d_out;

  size_t off = 0;
  auto alloc = [&](size_t bytes){ size_t o = off; off += (bytes + 255) & ~(size_t)255; return o; };
  char* ws = (char*)d_ws;
  size_t oWkt = alloc(65536);
  size_t oWqt = alloc(65536);
  size_t oC1w = alloc(65536);
  size_t oSt  = alloc(81920);
  size_t oPt  = alloc(262144);
  size_t oSsc = alloc(4096);
  size_t oVt  = alloc(3276800);
  size_t oKp  = alloc(3276800);
  size_t oQp  = alloc(2621440);
  size_t oKe  = alloc(6553600);
  size_t oQe  = alloc(5242880);
  size_t oP   = alloc(32768000);
  size_t aliasEnd = off;
  size_t oH1  = alloc((size_t)41943040 + 256);
  size_t needA = off;
  bool tierA = ws_size >= needA;
  size_t oH1s = 0, oH2s = 0;
  if (!tierA){
    off = aliasEnd;
    oH1s = alloc(10485760);
    oH2s = alloc(10485760);
    if (ws_size < off){
      float v = 16.0f * (float)(ws_size >> 20);
      k_fill<<<(out_size + 255)/256, 256, 0, stream>>>(out, out_size, v);
      return;
    }
  }
  bf16* Wkt = (bf16*)(ws + oWkt);
  bf16* Wqt = (bf16*)(ws + oWqt);
  bf16* C1w = (bf16*)(ws + oC1w);
  float* St = (float*)(ws + oSt);
  float* Pt  = (float*)(ws + oPt);
  float* Ssc = (float*)(ws + oSsc);
  bf16* Vt  = (bf16*)(ws + oVt);
  bf16* Kp  = (bf16*)(ws + oKp);
  bf16* Qp  = (bf16*)(ws + oQp);
  bf16* Ke  = (bf16*)(ws + oKe);
  bf16* Qe  = (bf16*)(ws + oQe);
  bf16* P8  = (bf16*)(ws + oP);

  k_prep<<<384, 256, 0, stream>>>(Wk, Wq, c1wf, Wkt, Wqt, C1w);

  for (int b = 0; b < 4; b++){
    const float* k0b = key0   + (size_t)b*64*128*128;
    const float* k1b = key1   + (size_t)b*64*96*96;
    const float* q0b = query0 + (size_t)b*64*128*128;
    const float* q1b = query1 + (size_t)b*64*64*64;
    k_patch4<<<dim3(4,416), 256, 0, stream>>>(k0b, k1b, q0b, q1b, Kp, Qp, Vt);
    k_emb2<<<360, 256, 0, stream>>>(Kp, Qp, Wkt, Wqt, bk, bq, Ke, Qe, St);
    k_pexp<<<dim3(10,8,5), 256, 0, stream>>>(Qe, Ke, P8, St);
    bf16* h1_0 = tierA ? (bf16*)(ws + oH1) + (size_t)b*16384*256
                       : (bf16*)(ws + oH1s);
    bf16* h1_1 = tierA ? (bf16*)(ws + oH1 + 33554432) + (size_t)b*4096*256
                       : (bf16*)(ws + oH1s + 8388608);
    k_wv<<<640, 512, 0, stream>>>(P8, Vt, C1w, c1b, St, h1_0, h1_1);
    if (!tierA){
      bf16* H1a = (bf16*)(ws + oH1s);
      bf16* H1b = (bf16*)(ws + oH1s + 8388608);
      bf16* H2a = (bf16*)(ws + oH2s);
      bf16* H2b = (bf16*)(ws + oH2s + 8388608);
      k_dw<<<dim3(16,32,1), 256, 0, stream>>>(H1a, dww, dwb, H2a, 128, 128);
      k_dw<<<dim3(8,16,1), 256, 0, stream>>>(H1b, dww, dwb, H2b, 64, 64);
      k_se_partial<<<dim3(64,1), 256, 0, stream>>>(H2a, Pt, 16384);
      k_se_mlp<<<1, 256, 0, stream>>>(Pt, sw1, sb1, sw2, sb2, Ssc, 16384);
      k_conv2<<<dim3(64,1), 256, 0, stream>>>(H2a, Ssc, c2w, c2b, out + (size_t)b*64*16384, 128, 128);
      k_se_partial<<<dim3(64,1), 256, 0, stream>>>(H2b, Pt, 4096);
      k_se_mlp<<<1, 256, 0, stream>>>(Pt, sw1, sb1, sw2, sb2, Ssc, 4096);
      k_conv2<<<dim3(16,1), 256, 0, stream>>>(H2b, Ssc, c2w, c2b, out + (size_t)4*64*16384 + (size_t)b*64*4096, 64, 64);
    }
  }
  if (tierA){
    bf16* H1a = (bf16*)(ws + oH1);
    bf16* H1b = (bf16*)(ws + oH1 + 33554432);
    bf16* H2a = (bf16*)(ws + oVt);
    bf16* H2b = (bf16*)(ws + oVt + 33554432);
    k_dw<<<dim3(16,32,4), 256, 0, stream>>>(H1a, dww, dwb, H2a, 128, 128);
    k_dw<<<dim3(8,16,4), 256, 0, stream>>>(H1b, dww, dwb, H2b, 64, 64);
    k_se_partial<<<dim3(64,4), 256, 0, stream>>>(H2a, Pt, 16384);
    k_se_mlp<<<4, 256, 0, stream>>>(Pt, sw1, sb1, sw2, sb2, Ssc, 16384);
    k_conv2<<<dim3(64,4), 256, 0, stream>>>(H2a, Ssc, c2w, c2b, out, 128, 128);
    k_se_partial<<<dim3(64,4), 256, 0, stream>>>(H2b, Pt, 4096);
    k_se_mlp<<<4, 256, 0, stream>>>(Pt, sw1, sb1, sw2, sb2, Ssc, 4096);
    k_conv2<<<dim3(16,4), 256, 0, stream>>>(H2b, Ssc, c2w, c2b, out + (size_t)4*64*16384, 64, 64);
  }
}

// Round 14
// 534.798 us; speedup vs baseline: 1.2443x; 1.0414x over previous
//
#include <hip/hip_runtime.h>
#include <hip/hip_bf16.h>

typedef __hip_bfloat16 bf16;
typedef short s8v __attribute__((ext_vector_type(8)));
typedef float f4v __attribute__((ext_vector_type(4)));

__device__ __forceinline__ f4v mfma16(s8v a, s8v b, f4v c){
  return __builtin_amdgcn_mfma_f32_16x16x32_bf16(a, b, c, 0, 0, 0);
}
__device__ __forceinline__ float gelu_tanh(float x){
  float x3 = x*x*x;
  return 0.5f*x*(1.0f + tanhf(0.7978845608028654f*(x + 0.044715f*x3)));
}

// ---------------- sentinel fill (encodes ws_size in MB * 16) ----------------
__global__ void k_fill(float* out, int n, float val){
  int i = blockIdx.x*256 + threadIdx.x;
  if (i < n) out[i] = val;
}

// ---------------- weight prep ----------------
__global__ __launch_bounds__(256) void k_prep(const float* __restrict__ Wk, const float* __restrict__ Wq,
                       const float* __restrict__ c1wf,
                       bf16* __restrict__ Wkt, bf16* __restrict__ Wqt, bf16* __restrict__ c1w){
  int tid = blockIdx.x*256 + threadIdx.x; // 98304 total
  if (tid < 32768){ int d = tid >> 7, j = tid & 127; Wkt[tid] = __float2bfloat16(Wk[j*256 + d]); }
  else if (tid < 65536){ int r = tid - 32768; int d = r >> 7, j = r & 127; Wqt[r] = __float2bfloat16(Wq[j*256 + d]); }
  else { int r = tid - 65536; c1w[r] = __float2bfloat16(c1wf[r]); }
}

// ---------------- fused patchify (one batch, all 4 tensors) ----------------
__global__ __launch_bounds__(256) void k_patch4(const float* __restrict__ k0, const float* __restrict__ k1,
                         const float* __restrict__ q0, const float* __restrict__ q1,
                         bf16* __restrict__ Kp, bf16* __restrict__ Qp, bf16* __restrict__ Vt){
  __shared__ float tile[64][33];
  int gy = blockIdx.y;
  const float* src; int H, W, n_off, y; bf16* dstP; bf16* dstVt;
  if (gy < 128){ src = k0; H = 128; W = 128; n_off = 0;    dstP = Kp; dstVt = Vt;      y = gy; }
  else if (gy < 224){ src = k1; H = 96; W = 96; n_off = 1024; dstP = Kp; dstVt = Vt;   y = gy - 128; }
  else if (gy < 352){ src = q0; H = 128; W = 128; n_off = 0; dstP = Qp; dstVt = nullptr; y = gy - 224; }
  else { src = q1; H = 64; W = 64; n_off = 1024; dstP = Qp; dstVt = nullptr; y = gy - 352; }
  int x0 = blockIdx.x*32;
  if (x0 >= W) return;
  int t = threadIdx.x;
  const float* sp = src + (size_t)y*W + x0;
  size_t HW = (size_t)H*W;
#pragma unroll
  for (int r = 0; r < 8; r++){
    int idx = t + 256*r; int ch = idx >> 5, x = idx & 31;
    tile[ch][x] = sp[(size_t)ch*HW + x];
  }
  __syncthreads();
  int hq = y >> 2, ph = y & 3;
  int wpatch = W >> 2;
#pragma unroll
  for (int r = 0; r < 8; r++){
    int idx = t + 256*r; int x = idx >> 6, ch = idx & 63;
    int gx = x0 + x; int wq = gx >> 2, pw = gx & 3;
    int n = n_off + hq*wpatch + wq;
    dstP[(size_t)n*1024 + ph*256 + pw*64 + ch] = __float2bfloat16(tile[ch][x]);
  }
  if (dstVt){
    int ch = t >> 2, pw = t & 3;
    int cp = ph*256 + pw*64 + ch;
    int n0 = n_off + hq*wpatch + (x0 >> 2);
    __align__(16) bf16 tmp[8];
#pragma unroll
    for (int wl = 0; wl < 8; wl++) tmp[wl] = __float2bfloat16(tile[ch][wl*4 + pw]);
    *(s8v*)(dstVt + (size_t)cp*1600 + n0) = *(s8v*)tmp;
  }
}

// ---------------- fused embedding GEMM (one batch, K+Q); also zeroes St slice ----------------
__global__ __launch_bounds__(256) void k_emb2(const bf16* __restrict__ Kp, const bf16* __restrict__ Qp,
                       const bf16* __restrict__ Wkt, const bf16* __restrict__ Wqt,
                       const float* __restrict__ bk, const float* __restrict__ bq,
                       bf16* __restrict__ Ke, bf16* __restrict__ Qe, float* __restrict__ St){
  if (blockIdx.x < 40) St[blockIdx.x*256 + threadIdx.x] = 0.f;
  int bx = blockIdx.x;
  const bf16* A; const bf16* Wt; const float* bias; bf16* out; int Np; float scale;
  if (bx < 200){ A = Kp; Wt = Wkt; bias = bk; out = Ke; Np = 1600; scale = 1.0f; }
  else { bx -= 200; A = Qp; Wt = Wqt; bias = bq; out = Qe; Np = 1280; scale = 0.17677669529663687f; }
  int t = threadIdx.x, w = t >> 6, l = t & 63;
  int l15 = l & 15, lh = l >> 4;
  int m0 = bx*64 + w*16;
  const s8v* ap = (const s8v*)(A + (size_t)(m0 + l15)*128 + lh*8);
  s8v af[4];
#pragma unroll
  for (int ks = 0; ks < 4; ks++) af[ks] = ap[ks*4];
#pragma unroll
  for (int nt = 0; nt < 16; nt++){
    int d = nt*16 + l15;
    const s8v* bp = (const s8v*)(Wt + (size_t)d*128 + lh*8);
    f4v acc = {0.f,0.f,0.f,0.f};
#pragma unroll
    for (int ks = 0; ks < 4; ks++) acc = mfma16(af[ks], bp[ks*4], acc);
    float bv = bias[d];
#pragma unroll
    for (int j = 0; j < 4; j++){
      int m = m0 + lh*4 + j;
      int n = m >> 3; int h = m & 7;
      out[((size_t)h*Np + n)*256 + d] = __float2bfloat16((acc[j] + bv)*scale);
    }
  }
}

// ---------------- fused logits -> exp (no max-sub) -> Pexp bf16 + row-sum atomics ----------------
// grid (qt=10, h=8, kc=5): block covers 128 q-rows x 320 keys (5 kt of 64); K-tile reg-prefetched
__global__ __launch_bounds__(256) void k_pexp(const bf16* __restrict__ Qe, const bf16* __restrict__ Ke,
                      bf16* __restrict__ P, float* __restrict__ St){
  __shared__ bf16 Ks[64][264];
  __shared__ bf16 Pw[4][32][134];
  int t = threadIdx.x, w = t >> 6, l = t & 63, l15 = l & 15, lh = l >> 4;
  int qt = blockIdx.x, h = blockIdx.y, kc = blockIdx.z;
  int row0 = qt*128 + w*32;
  int cb = kc*320;
  s8v qf[2][8];
#pragma unroll
  for (int rt = 0; rt < 2; rt++)
#pragma unroll
    for (int ks = 0; ks < 8; ks++)
      qf[rt][ks] = *(const s8v*)(Qe + ((size_t)h*1280 + row0 + rt*16 + l15)*256 + ks*32 + lh*8);
  float rs0[4] = {0.f,0.f,0.f,0.f}, rs1[4] = {0.f,0.f,0.f,0.f};
  int kr = t >> 2, kq = t & 3;
  size_t prow_base = (size_t)h*1280 + row0;
  s8v kreg[8];
  {
    const bf16* s0 = Ke + ((size_t)h*1600 + kc*320 + kr)*256 + kq*64;
#pragma unroll
    for (int u = 0; u < 8; u++) kreg[u] = *(const s8v*)(s0 + u*8);
  }
  for (int i = 0; i < 5; i++){
    if (i) __syncthreads();
#pragma unroll
    for (int u = 0; u < 8; u++){
      int sw = (kq*8 + u) ^ (kr & 7);
      *(s8v*)&Ks[kr][sw*8] = kreg[u];
    }
    if (i < 4){
      const bf16* sn = Ke + ((size_t)h*1600 + kc*320 + (i+1)*64 + kr)*256 + kq*64;
#pragma unroll
      for (int u = 0; u < 8; u++) kreg[u] = *(const s8v*)(sn + u*8);
    }
    __syncthreads();
    f4v a0[4], a1[4];
#pragma unroll
    for (int ct = 0; ct < 4; ct++){ a0[ct] = (f4v){0.f,0.f,0.f,0.f}; a1[ct] = (f4v){0.f,0.f,0.f,0.f}; }
#pragma unroll
    for (int ct = 0; ct < 4; ct++){
      int krow = ct*16 + l15;
#pragma unroll
      for (int ks = 0; ks < 8; ks++){
        s8v bf = *(const s8v*)&Ks[krow][((ks*4 + lh) ^ (krow & 7))*8];
        a0[ct] = mfma16(qf[0][ks], bf, a0[ct]);
        a1[ct] = mfma16(qf[1][ks], bf, a1[ct]);
      }
    }
#pragma unroll
    for (int ct = 0; ct < 4; ct++){
      int local = (i*4 + ct) & 7;
#pragma unroll
      for (int j = 0; j < 4; j++){
        float e0 = __expf(a0[ct][j]); rs0[j] += e0;
        float e1 = __expf(a1[ct][j]); rs1[j] += e1;
        Pw[w][lh*4 + j][local*16 + l15]      = __float2bfloat16(e0);
        Pw[w][16 + lh*4 + j][local*16 + l15] = __float2bfloat16(e1);
      }
    }
    if (i & 1){
      int ci = i >> 1;
#pragma unroll
      for (int p = 0; p < 8; p++){
        int s = p*8 + (l >> 3);
        int row = s >> 1, half = s & 1;
        *(uint4*)(P + (prow_base + row)*1600 + cb + ci*128 + half*64 + (l & 7)*8) =
          *(uint4*)&Pw[w][row][half*64 + (l & 7)*8];
      }
    }
  }
#pragma unroll
  for (int p = 0; p < 4; p++){
    int row = p*8 + (l >> 3);
    *(uint4*)(P + (prow_base + row)*1600 + cb + 256 + (l & 7)*8) =
      *(uint4*)&Pw[w][row][(l & 7)*8];
  }
#pragma unroll
  for (int j = 0; j < 4; j++){
    float s0 = rs0[j], s1 = rs1[j];
#pragma unroll
    for (int d = 1; d < 16; d <<= 1){ s0 += __shfl_xor(s0, d); s1 += __shfl_xor(s1, d); }
    if (l15 == 0){
      atomicAdd(&St[(size_t)h*1280 + row0 + lh*4 + j], s0);
      atomicAdd(&St[(size_t)h*1280 + row0 + 16 + lh*4 + j], s1);
    }
  }
}

// ---------------- wv GEMM (nb batches) + deferred softmax-norm + fused conv1+GELU -> H1 ----------------
// 512 threads, tile 128x128, BK=64, grid 640*nb: h=bid&7, nt=(bid>>3)&7, b2=(bid>>6)&nbm1, mt=bid>>mtsh.
__global__ __launch_bounds__(512, 4) void k_wv(const bf16* __restrict__ P, const bf16* __restrict__ Vt,
                     const bf16* __restrict__ c1w, const float* __restrict__ c1b,
                     const float* __restrict__ St,
                     bf16* __restrict__ h1_0, bf16* __restrict__ h1_1,
                     int nbm1, int mtsh){
  __shared__ bf16 AB[16384];   // A[128][64]@0, B[128][64]@8192; union: Ot[256][64]
  __shared__ bf16 W1s[4096];   // [32][128] swizzled (granule ^ (row&7))
  int bid = blockIdx.x;
  int h  = bid & 7;
  int nt = (bid >> 3) & 7;
  int b2 = (bid >> 6) & nbm1;
  int mt = bid >> mtsh;
  int t = threadIdx.x, w = t >> 6, l = t & 63;
  int l15 = l & 15, lh = l >> 4;
  int wr = w >> 2, wc = w & 3;
  {
    int rr = t >> 4;            // 0..31
    int gp = t & 15;            // 0..15
    *(uint4*)&W1s[rr*128 + ((gp ^ (rr & 7))*8)] =
      *(const uint4*)(c1w + ((size_t)h*32 + rr)*128 + gp*8);
  }
  const float* Stb = St + (size_t)b2*10240;
  bf16* hb0 = h1_0 + (size_t)b2*4194304;
  bf16* hb1 = h1_1 + (size_t)b2*1048576;
  const bf16* Ab = P + (size_t)b2*16384000 + ((size_t)h*1280 + mt*128)*1600;
  const bf16* Bb = Vt + (size_t)b2*1638400 + ((size_t)nt*128)*1600;
  int srow = t >> 2;
  int g0 = (t & 3)*2;
  int key = srow & 7;
  const bf16* gAp = Ab + (size_t)srow*1600 + g0*8;
  const bf16* gBp = Bb + (size_t)srow*1600 + g0*8;
  int da0 = srow*64 + (((g0+0) ^ key)*8);
  int da1 = srow*64 + (((g0+1) ^ key)*8);
  f4v acc2[2][2];
#pragma unroll
  for (int mm = 0; mm < 2; mm++)
#pragma unroll
    for (int nn = 0; nn < 2; nn++) acc2[mm][nn] = (f4v){0.f,0.f,0.f,0.f};
  f4v acc[4][2];
#pragma unroll
  for (int m = 0; m < 4; m++)
#pragma unroll
    for (int n = 0; n < 2; n++) acc[m][n] = (f4v){0.f,0.f,0.f,0.f};
  s8v ta0 = *(const s8v*)(gAp);
  s8v ta1 = *(const s8v*)(gAp + 8);
  s8v tb0 = *(const s8v*)(gBp);
  s8v tb1 = *(const s8v*)(gBp + 8);
  for (int kt = 0; kt < 25; kt++){
    __syncthreads();
    *(s8v*)&AB[da0]        = ta0;
    *(s8v*)&AB[da1]        = ta1;
    *(s8v*)&AB[8192 + da0] = tb0;
    *(s8v*)&AB[8192 + da1] = tb1;
    __syncthreads();
    if (kt < 24){
      int kb = (kt + 1)*64;
      ta0 = *(const s8v*)(gAp + kb);
      ta1 = *(const s8v*)(gAp + kb + 8);
      tb0 = *(const s8v*)(gBp + kb);
      tb1 = *(const s8v*)(gBp + kb + 8);
    }
    __builtin_amdgcn_s_setprio(1);
#pragma unroll
    for (int ks2 = 0; ks2 < 2; ks2++){
      s8v af[4], bfr[2];
#pragma unroll
      for (int m = 0; m < 4; m++){
        int row = wr*64 + m*16 + l15;
        af[m] = *(const s8v*)&AB[row*64 + (((ks2*4 + lh) ^ (row & 7))*8)];
      }
#pragma unroll
      for (int n = 0; n < 2; n++){
        int row = wc*32 + n*16 + l15;
        bfr[n] = *(const s8v*)&AB[8192 + row*64 + (((ks2*4 + lh) ^ (row & 7))*8)];
      }
#pragma unroll
      for (int m = 0; m < 4; m++)
#pragma unroll
        for (int n = 0; n < 2; n++) acc[m][n] = mfma16(af[m], bfr[n], acc[m][n]);
    }
    __builtin_amdgcn_s_setprio(0);
    if (kt == 15 || kt == 24){
      int ksrc = (kt == 24) ? 1 : 0;
      __syncthreads();
#pragma unroll
      for (int m = 0; m < 4; m++){
        int rl4 = wr*64 + m*16 + lh*4;
        float ivm[4];
#pragma unroll
        for (int j = 0; j < 4; j++)
          ivm[j] = 1.0f / Stb[(size_t)h*1280 + mt*128 + rl4 + j];
#pragma unroll
        for (int n = 0; n < 2; n++){
          int c = wc*32 + n*16 + l15;     // 0..127
          int cellL = c >> 6, ch = c & 63;
#pragma unroll
          for (int j = 0; j < 4; j++){
            int p = (rl4 + j)*2 + cellL;
            AB[p*64 + (((ch >> 3) ^ (p & 7))*8) + (ch & 7)] = __float2bfloat16(acc[m][n][j]*ivm[j]);
          }
        }
      }
      __syncthreads();
      __builtin_amdgcn_s_setprio(1);
#pragma unroll
      for (int ks2 = 0; ks2 < 2; ks2++){
        s8v afc[2], bfc[2];
#pragma unroll
        for (int mm = 0; mm < 2; mm++){
          int p2 = w*32 + mm*16 + l15;   // 0..255
          afc[mm] = *(const s8v*)&AB[p2*64 + (((ks2*4 + lh) ^ (p2 & 7))*8)];
        }
#pragma unroll
        for (int nn = 0; nn < 2; nn++){
          int rw = nn*16 + l15;
          int gg = ksrc*8 + ks2*4 + lh;
          bfc[nn] = *(const s8v*)&W1s[rw*128 + ((gg ^ (rw & 7))*8)];
        }
#pragma unroll
        for (int mm = 0; mm < 2; mm++)
#pragma unroll
          for (int nn = 0; nn < 2; nn++)
            acc2[mm][nn] = mfma16(afc[mm], bfc[nn], acc2[mm][nn]);
      }
      __builtin_amdgcn_s_setprio(0);
      if (kt == 15){
#pragma unroll
        for (int m = 0; m < 4; m++)
#pragma unroll
          for (int n = 0; n < 2; n++) acc[m][n] = (f4v){0.f,0.f,0.f,0.f};
      }
    }
  }
  float bia[2];
#pragma unroll
  for (int nn = 0; nn < 2; nn++) bia[nn] = c1b[h*32 + nn*16 + l15];
#pragma unroll
  for (int mm = 0; mm < 2; mm++){
#pragma unroll
    for (int nn = 0; nn < 2; nn++){
#pragma unroll
      for (int j = 0; j < 4; j++){
        float v = gelu_tanh(acc2[mm][nn][j] + bia[nn]);
        int p2 = w*32 + mm*16 + lh*4 + j;   // 0..255
        int rl = p2 >> 1, cellL = p2 & 1;
        int rq = mt*128 + rl;
        int cell = nt*2 + cellL; int ph = cell >> 2, pw = cell & 3;
        int o = h*32 + nn*16 + l15;
        if (rq < 1024){
          int y = ((rq >> 5) << 2) + ph, x = ((rq & 31) << 2) + pw;
          hb0[((size_t)y*128 + x)*256 + o] = __float2bfloat16(v);
        } else {
          int r2 = rq - 1024;
          int y = ((r2 >> 4) << 2) + ph, x = ((r2 & 15) << 2) + pw;
          hb1[((size_t)y*64 + x)*256 + o] = __float2bfloat16(v);
        }
      }
    }
  }
}

// ---------------- depthwise 3x3 + GELU, NHWC: weights in REGISTERS (no LDS, no bank conflicts) ----------------
__global__ __launch_bounds__(256) void k_dw(const bf16* __restrict__ h1, const float* __restrict__ wdw,
                     const float* __restrict__ bdw, bf16* __restrict__ h2, int H, int W){
  int t = threadIdx.x;
  int cg = t & 31, xo = t >> 5;
  int ch0 = cg*8;
  int x = blockIdx.x*8 + xo;
  int y0 = blockIdx.y*4;
  int b = blockIdx.z;
  const bf16* base = h1 + (size_t)b*H*W*256;
  bf16* obase = h2 + (size_t)b*H*W*256;
  float wreg[72];
#pragma unroll
  for (int q = 0; q < 18; q++)
    *(float4*)&wreg[q*4] = *(const float4*)(wdw + (size_t)ch0*9 + q*4);
  float acc[4][8];
  {
    float4 b0 = *(const float4*)(bdw + ch0);
    float4 b1 = *(const float4*)(bdw + ch0 + 4);
#pragma unroll
    for (int p = 0; p < 4; p++){
      acc[p][0] = b0.x; acc[p][1] = b0.y; acc[p][2] = b0.z; acc[p][3] = b0.w;
      acc[p][4] = b1.x; acc[p][5] = b1.y; acc[p][6] = b1.z; acc[p][7] = b1.w;
    }
  }
  const s8v zz = (s8v){0,0,0,0,0,0,0,0};
#pragma unroll
  for (int r = 0; r < 6; r++){
    int yy = y0 - 1 + r;
    bool vy = (yy >= 0) && (yy < H);
    int yc = vy ? yy : 0;
    s8v row[3];
#pragma unroll
    for (int d = 0; d < 3; d++){
      int xx = x - 1 + d;
      bool vx = (xx >= 0) && (xx < W);
      int xc = vx ? xx : 0;
      s8v v = *(const s8v*)(base + ((size_t)yc*W + xc)*256 + ch0);
      row[d] = (vy && vx) ? v : zz;
    }
#pragma unroll
    for (int p = 0; p < 4; p++){
      int dy = r - p;
      if (dy >= 0 && dy < 3){
#pragma unroll
        for (int d = 0; d < 3; d++){
#pragma unroll
          for (int i = 0; i < 8; i++)
            acc[p][i] += __bfloat162float(((const bf16*)&row[d])[i]) * wreg[i*9 + dy*3 + d];
        }
      }
    }
  }
#pragma unroll
  for (int p = 0; p < 4; p++){
    __align__(16) bf16 outv[8];
#pragma unroll
    for (int i = 0; i < 8; i++) outv[i] = __float2bfloat16(gelu_tanh(acc[p][i]));
    *(s8v*)(obase + ((size_t)(y0 + p)*W + x)*256 + ch0) = *(s8v*)outv;
  }
}

// ---------------- SE partial sums, grid (64, nb), vectorized ----------------
__global__ __launch_bounds__(256) void k_se_partial(const bf16* __restrict__ h2, float* __restrict__ partial, int HW){
  __shared__ float red[8][256];
  int chunk = blockIdx.x, b = blockIdx.y, t = threadIdx.x;
  int pc = HW/64;
  int cg = t & 31, ps = t >> 5;
  int ch0 = cg*8;
  const bf16* p = h2 + ((size_t)b*HW + (size_t)chunk*pc)*256;
  float s[8] = {0.f,0.f,0.f,0.f,0.f,0.f,0.f,0.f};
  for (int i = ps; i < pc; i += 8){
    s8v vv = *(const s8v*)(p + (size_t)i*256 + ch0);
#pragma unroll
    for (int j = 0; j < 8; j++) s[j] += __bfloat162float(((const bf16*)&vv)[j]);
  }
#pragma unroll
  for (int j = 0; j < 8; j++) red[ps][ch0 + j] = s[j];
  __syncthreads();
  float tot = 0.f;
#pragma unroll
  for (int r = 0; r < 8; r++) tot += red[r][t];
  partial[((size_t)b*64 + chunk)*256 + t] = tot;
}

// ---------------- SE MLP, grid (nb) ----------------
__global__ __launch_bounds__(256) void k_se_mlp(const float* __restrict__ partial, const float* __restrict__ w1,
                         const float* __restrict__ b1, const float* __restrict__ w2, const float* __restrict__ b2,
                         float* __restrict__ sca, int HW){
  __shared__ float mean[256];
  __shared__ float s1[64];
  int b = blockIdx.x, t = threadIdx.x;
  float s = 0.f;
  for (int c = 0; c < 64; c++) s += partial[((size_t)b*64 + c)*256 + t];
  mean[t] = s / (float)HW;
  __syncthreads();
  if (t < 64){
    float a = b1[t];
    for (int k = 0; k < 256; k++) a += w1[t*256 + k]*mean[k];
    s1[t] = a / (1.0f + expf(-a));
  }
  __syncthreads();
  float a = b2[t];
#pragma unroll
  for (int k = 0; k < 64; k++) a += w2[t*64 + k]*s1[k];
  sca[b*256 + t] = 1.0f/(1.0f + expf(-a));
}

// ---------------- SE scale + conv2 -> NCHW f32, grid (HW/256, nb) ----------------
__global__ __launch_bounds__(256) void k_conv2(const bf16* __restrict__ h2, const float* __restrict__ sca,
                        const float* __restrict__ w2c, const float* __restrict__ b2c,
                        float* __restrict__ out, int H, int W){
  __shared__ float wsm[64][32];
  __shared__ float scs[256];
  int t = threadIdx.x, b = blockIdx.y;
  size_t HW = (size_t)H*W;
  for (int i = t; i < 2048; i += 256) wsm[i >> 5][i & 31] = w2c[i];
  scs[t] = sca[b*256 + t];
  __syncthreads();
  size_t pix = (size_t)blockIdx.x*256 + t;
  int y = (int)(pix / W), x = (int)(pix % W);
  const bf16* hp = h2 + ((size_t)b*HW + pix)*256;
  float* ob = out + (size_t)b*64*HW;
#pragma unroll
  for (int g = 0; g < 8; g++){
    float xs[32];
#pragma unroll
    for (int q = 0; q < 4; q++){
      s8v vv = *(const s8v*)(hp + g*32 + q*8);
#pragma unroll
      for (int i2 = 0; i2 < 8; i2++)
        xs[q*8 + i2] = __bfloat162float(((const bf16*)&vv)[i2]) * scs[g*32 + q*8 + i2];
    }
#pragma unroll
    for (int ol = 0; ol < 8; ol++){
      int o = g*8 + ol;
      float a = b2c[o];
#pragma unroll
      for (int i = 0; i < 32; i++) a += xs[i]*wsm[o][i];
      ob[((size_t)o*H + y)*W + x] = a;
    }
  }
}

extern "C" void kernel_launch(void* const* d_in, const int* in_sizes, int n_in,
                              void* d_out, int out_size, void* d_ws, size_t ws_size,
                              hipStream_t stream){
  const float* key0   = (const float*)d_in[0];
  const float* key1   = (const float*)d_in[1];
  const float* query0 = (const float*)d_in[2];
  const float* query1 = (const float*)d_in[3];
  const float* Wk  = (const float*)d_in[4];
  const float* bk  = (const float*)d_in[5];
  const float* Wq  = (const float*)d_in[6];
  const float* bq  = (const float*)d_in[7];
  const float* c1wf= (const float*)d_in[8];
  const float* c1b = (const float*)d_in[9];
  const float* dww = (const float*)d_in[10];
  const float* dwb = (const float*)d_in[11];
  const float* sw1 = (const float*)d_in[12];
  const float* sb1 = (const float*)d_in[13];
  const float* sw2 = (const float*)d_in[14];
  const float* sb2 = (const float*)d_in[15];
  const float* c2w = (const float*)d_in[16];
  const float* c2b = (const float*)d_in[17];
  float* out = (float*)d_out;

  // fixed region
  size_t oWkt = 0, oWqt = 65536, oC1w = 131072, oSt = 196608, oPt = 360448, oSsc = 622592;
  size_t fixedEnd = 626688;
  // tiered plan: nb batches of P/Vt resident simultaneously
  size_t oVt, oKp, oQp, oKe, oQe, oP, oH1;
  auto plan = [&](int nb)->size_t{
    size_t o = fixedEnd;
    oVt = o; o += (size_t)nb*3276800;
    oKp = o; o += 3276800;
    oQp = o; o += 2621440;
    oKe = o; o += 6553600;
    oQe = o; o += 5242880;
    oP  = o; o += (size_t)nb*32768000;
    oH1 = o; o += 41943296;
    return o;
  };
  int nb = 1;
  if (plan(4) <= ws_size) nb = 4;
  else if (plan(2) <= ws_size) nb = 2;
  else if (plan(1) <= ws_size) nb = 1;
  else {
    float v = 16.0f * (float)(ws_size >> 20);
    k_fill<<<(out_size + 255)/256, 256, 0, stream>>>(out, out_size, v);
    return;
  }
  plan(nb);
  char* ws = (char*)d_ws;
  bf16* Wkt = (bf16*)(ws + oWkt);
  bf16* Wqt = (bf16*)(ws + oWqt);
  bf16* C1w = (bf16*)(ws + oC1w);
  float* St = (float*)(ws + oSt);
  float* Pt  = (float*)(ws + oPt);
  float* Ssc = (float*)(ws + oSsc);
  bf16* Vt  = (bf16*)(ws + oVt);
  bf16* Kp  = (bf16*)(ws + oKp);
  bf16* Qp  = (bf16*)(ws + oQp);
  bf16* Ke  = (bf16*)(ws + oKe);
  bf16* Qe  = (bf16*)(ws + oQe);
  bf16* P8  = (bf16*)(ws + oP);
  bf16* H1a = (bf16*)(ws + oH1);
  bf16* H1b = (bf16*)(ws + oH1 + 33554432);

  k_prep<<<384, 256, 0, stream>>>(Wk, Wq, c1wf, Wkt, Wqt, C1w);

  int mtsh = (nb == 4) ? 8 : (nb == 2) ? 7 : 6;
  for (int g = 0; g < 4; g += nb){
    for (int sub = 0; sub < nb; sub++){
      int b = g + sub;
      const float* k0b = key0   + (size_t)b*64*128*128;
      const float* k1b = key1   + (size_t)b*64*96*96;
      const float* q0b = query0 + (size_t)b*64*128*128;
      const float* q1b = query1 + (size_t)b*64*64*64;
      bf16* Vtb = Vt + (size_t)sub*1638400;
      float* Stb = St + (size_t)sub*10240;
      bf16* Pb  = P8 + (size_t)sub*16384000;
      k_patch4<<<dim3(4,416), 256, 0, stream>>>(k0b, k1b, q0b, q1b, Kp, Qp, Vtb);
      k_emb2<<<360, 256, 0, stream>>>(Kp, Qp, Wkt, Wqt, bk, bq, Ke, Qe, Stb);
      k_pexp<<<dim3(10,8,5), 256, 0, stream>>>(Qe, Ke, Pb, Stb);
    }
    k_wv<<<640*nb, 512, 0, stream>>>(P8, Vt, C1w, c1b, St,
                                     H1a + (size_t)g*4194304, H1b + (size_t)g*1048576,
                                     nb - 1, mtsh);
  }
  // conv tail (batched over all 4): H2 aliases dead Vt..P region
  bf16* H2a = (bf16*)(ws + oVt);
  bf16* H2b = (bf16*)(ws + oVt + 33554432);
  k_dw<<<dim3(16,32,4), 256, 0, stream>>>(H1a, dww, dwb, H2a, 128, 128);
  k_dw<<<dim3(8,16,4), 256, 0, stream>>>(H1b, dww, dwb, H2b, 64, 64);
  k_se_partial<<<dim3(64,4), 256, 0, stream>>>(H2a, Pt, 16384);
  k_se_mlp<<<4, 256, 0, stream>>>(Pt, sw1, sb1, sw2, sb2, Ssc, 16384);
  k_conv2<<<dim3(64,4), 256, 0, stream>>>(H2a, Ssc, c2w, c2b, out, 128, 128);
  k_se_partial<<<dim3(64,4), 256, 0, stream>>>(H2b, Pt, 4096);
  k_se_mlp<<<4, 256, 0, stream>>>(Pt, sw1, sb1, sw2, sb2, Ssc, 4096);
  k_conv2<<<dim3(16,4), 256, 0, stream>>>(H2b, Ssc, c2w, c2b, out + (size_t)4*64*16384, 64, 64);
}

// Round 15
// 489.856 us; speedup vs baseline: 1.3584x; 1.0917x over previous
//
#include <hip/hip_runtime.h>
#include <hip/hip_bf16.h>

typedef __hip_bfloat16 bf16;
typedef short s8v __attribute__((ext_vector_type(8)));
typedef float f4v __attribute__((ext_vector_type(4)));

__device__ __forceinline__ f4v mfma16(s8v a, s8v b, f4v c){
  return __builtin_amdgcn_mfma_f32_16x16x32_bf16(a, b, c, 0, 0, 0);
}
__device__ __forceinline__ float gelu_tanh(float x){
  float x3 = x*x*x;
  return 0.5f*x*(1.0f + tanhf(0.7978845608028654f*(x + 0.044715f*x3)));
}

// ---------------- sentinel fill (encodes ws_size in MB * 16) ----------------
__global__ void k_fill(float* out, int n, float val){
  int i = blockIdx.x*256 + threadIdx.x;
  if (i < n) out[i] = val;
}

// ---------------- weight prep ----------------
__global__ __launch_bounds__(256) void k_prep(const float* __restrict__ Wk, const float* __restrict__ Wq,
                       const float* __restrict__ c1wf,
                       bf16* __restrict__ Wkt, bf16* __restrict__ Wqt, bf16* __restrict__ c1w){
  int tid = blockIdx.x*256 + threadIdx.x; // 98304 total
  if (tid < 32768){ int d = tid >> 7, j = tid & 127; Wkt[tid] = __float2bfloat16(Wk[j*256 + d]); }
  else if (tid < 65536){ int r = tid - 32768; int d = r >> 7, j = r & 127; Wqt[r] = __float2bfloat16(Wq[j*256 + d]); }
  else { int r = tid - 65536; c1w[r] = __float2bfloat16(c1wf[r]); }
}

// ---------------- fused patchify (one batch, all 4 tensors) ----------------
__global__ __launch_bounds__(256) void k_patch4(const float* __restrict__ k0, const float* __restrict__ k1,
                         const float* __restrict__ q0, const float* __restrict__ q1,
                         bf16* __restrict__ Kp, bf16* __restrict__ Qp, bf16* __restrict__ Vt){
  __shared__ float tile[64][33];
  int gy = blockIdx.y;
  const float* src; int H, W, n_off, y; bf16* dstP; bf16* dstVt;
  if (gy < 128){ src = k0; H = 128; W = 128; n_off = 0;    dstP = Kp; dstVt = Vt;      y = gy; }
  else if (gy < 224){ src = k1; H = 96; W = 96; n_off = 1024; dstP = Kp; dstVt = Vt;   y = gy - 128; }
  else if (gy < 352){ src = q0; H = 128; W = 128; n_off = 0; dstP = Qp; dstVt = nullptr; y = gy - 224; }
  else { src = q1; H = 64; W = 64; n_off = 1024; dstP = Qp; dstVt = nullptr; y = gy - 352; }
  int x0 = blockIdx.x*32;
  if (x0 >= W) return;
  int t = threadIdx.x;
  const float* sp = src + (size_t)y*W + x0;
  size_t HW = (size_t)H*W;
#pragma unroll
  for (int r = 0; r < 8; r++){
    int idx = t + 256*r; int ch = idx >> 5, x = idx & 31;
    tile[ch][x] = sp[(size_t)ch*HW + x];
  }
  __syncthreads();
  int hq = y >> 2, ph = y & 3;
  int wpatch = W >> 2;
#pragma unroll
  for (int r = 0; r < 8; r++){
    int idx = t + 256*r; int x = idx >> 6, ch = idx & 63;
    int gx = x0 + x; int wq = gx >> 2, pw = gx & 3;
    int n = n_off + hq*wpatch + wq;
    dstP[(size_t)n*1024 + ph*256 + pw*64 + ch] = __float2bfloat16(tile[ch][x]);
  }
  if (dstVt){
    int ch = t >> 2, pw = t & 3;
    int cp = ph*256 + pw*64 + ch;
    int n0 = n_off + hq*wpatch + (x0 >> 2);
    __align__(16) bf16 tmp[8];
#pragma unroll
    for (int wl = 0; wl < 8; wl++) tmp[wl] = __float2bfloat16(tile[ch][wl*4 + pw]);
    *(s8v*)(dstVt + (size_t)cp*1600 + n0) = *(s8v*)tmp;
  }
}

// ---------------- fused embedding GEMM (one batch, K+Q); also zeroes St slice ----------------
__global__ __launch_bounds__(256) void k_emb2(const bf16* __restrict__ Kp, const bf16* __restrict__ Qp,
                       const bf16* __restrict__ Wkt, const bf16* __restrict__ Wqt,
                       const float* __restrict__ bk, const float* __restrict__ bq,
                       bf16* __restrict__ Ke, bf16* __restrict__ Qe, float* __restrict__ St){
  if (blockIdx.x < 40) St[blockIdx.x*256 + threadIdx.x] = 0.f;
  int bx = blockIdx.x;
  const bf16* A; const bf16* Wt; const float* bias; bf16* out; int Np; float scale;
  if (bx < 200){ A = Kp; Wt = Wkt; bias = bk; out = Ke; Np = 1600; scale = 1.0f; }
  else { bx -= 200; A = Qp; Wt = Wqt; bias = bq; out = Qe; Np = 1280; scale = 0.17677669529663687f; }
  int t = threadIdx.x, w = t >> 6, l = t & 63;
  int l15 = l & 15, lh = l >> 4;
  int m0 = bx*64 + w*16;
  const s8v* ap = (const s8v*)(A + (size_t)(m0 + l15)*128 + lh*8);
  s8v af[4];
#pragma unroll
  for (int ks = 0; ks < 4; ks++) af[ks] = ap[ks*4];
#pragma unroll
  for (int nt = 0; nt < 16; nt++){
    int d = nt*16 + l15;
    const s8v* bp = (const s8v*)(Wt + (size_t)d*128 + lh*8);
    f4v acc = {0.f,0.f,0.f,0.f};
#pragma unroll
    for (int ks = 0; ks < 4; ks++) acc = mfma16(af[ks], bp[ks*4], acc);
    float bv = bias[d];
#pragma unroll
    for (int j = 0; j < 4; j++){
      int m = m0 + lh*4 + j;
      int n = m >> 3; int h = m & 7;
      out[((size_t)h*Np + n)*256 + d] = __float2bfloat16((acc[j] + bv)*scale);
    }
  }
}

// ---------------- fused logits -> exp (no max-sub) -> Pexp bf16 + row-sum atomics ----------------
// grid (qt=10, h=8, z=5*nbp): b2 = z/5, kc = z%5; per-batch strides applied via b2
__global__ __launch_bounds__(256) void k_pexp(const bf16* __restrict__ Qe, const bf16* __restrict__ Ke,
                      bf16* __restrict__ P, float* __restrict__ St){
  __shared__ bf16 Ks[64][264];
  __shared__ bf16 Pw[4][32][134];
  int t = threadIdx.x, w = t >> 6, l = t & 63, l15 = l & 15, lh = l >> 4;
  int qt = blockIdx.x, h = blockIdx.y;
  int zz2 = blockIdx.z;
  int b2 = zz2 / 5, kc = zz2 - b2*5;
  const bf16* Qeb = Qe + (size_t)b2*2621440;
  const bf16* Keb = Ke + (size_t)b2*3276800;
  bf16* Pb = P + (size_t)b2*16384000;
  float* Stb = St + (size_t)b2*10240;
  int row0 = qt*128 + w*32;
  int cb = kc*320;
  s8v qf[2][8];
#pragma unroll
  for (int rt = 0; rt < 2; rt++)
#pragma unroll
    for (int ks = 0; ks < 8; ks++)
      qf[rt][ks] = *(const s8v*)(Qeb + ((size_t)h*1280 + row0 + rt*16 + l15)*256 + ks*32 + lh*8);
  float rs0[4] = {0.f,0.f,0.f,0.f}, rs1[4] = {0.f,0.f,0.f,0.f};
  int kr = t >> 2, kq = t & 3;
  size_t prow_base = (size_t)h*1280 + row0;
  s8v kreg[8];
  {
    const bf16* s0 = Keb + ((size_t)h*1600 + kc*320 + kr)*256 + kq*64;
#pragma unroll
    for (int u = 0; u < 8; u++) kreg[u] = *(const s8v*)(s0 + u*8);
  }
  for (int i = 0; i < 5; i++){
    if (i) __syncthreads();
#pragma unroll
    for (int u = 0; u < 8; u++){
      int sw = (kq*8 + u) ^ (kr & 7);
      *(s8v*)&Ks[kr][sw*8] = kreg[u];
    }
    if (i < 4){
      const bf16* sn = Keb + ((size_t)h*1600 + kc*320 + (i+1)*64 + kr)*256 + kq*64;
#pragma unroll
      for (int u = 0; u < 8; u++) kreg[u] = *(const s8v*)(sn + u*8);
    }
    __syncthreads();
    f4v a0[4], a1[4];
#pragma unroll
    for (int ct = 0; ct < 4; ct++){ a0[ct] = (f4v){0.f,0.f,0.f,0.f}; a1[ct] = (f4v){0.f,0.f,0.f,0.f}; }
#pragma unroll
    for (int ct = 0; ct < 4; ct++){
      int krow = ct*16 + l15;
#pragma unroll
      for (int ks = 0; ks < 8; ks++){
        s8v bf = *(const s8v*)&Ks[krow][((ks*4 + lh) ^ (krow & 7))*8];
        a0[ct] = mfma16(qf[0][ks], bf, a0[ct]);
        a1[ct] = mfma16(qf[1][ks], bf, a1[ct]);
      }
    }
#pragma unroll
    for (int ct = 0; ct < 4; ct++){
      int local = (i*4 + ct) & 7;
#pragma unroll
      for (int j = 0; j < 4; j++){
        float e0 = __expf(a0[ct][j]); rs0[j] += e0;
        float e1 = __expf(a1[ct][j]); rs1[j] += e1;
        Pw[w][lh*4 + j][local*16 + l15]      = __float2bfloat16(e0);
        Pw[w][16 + lh*4 + j][local*16 + l15] = __float2bfloat16(e1);
      }
    }
    if (i & 1){
      int ci = i >> 1;
#pragma unroll
      for (int p = 0; p < 8; p++){
        int s = p*8 + (l >> 3);
        int row = s >> 1, half = s & 1;
        *(uint4*)(Pb + (prow_base + row)*1600 + cb + ci*128 + half*64 + (l & 7)*8) =
          *(uint4*)&Pw[w][row][half*64 + (l & 7)*8];
      }
    }
  }
#pragma unroll
  for (int p = 0; p < 4; p++){
    int row = p*8 + (l >> 3);
    *(uint4*)(Pb + (prow_base + row)*1600 + cb + 256 + (l & 7)*8) =
      *(uint4*)&Pw[w][row][(l & 7)*8];
  }
#pragma unroll
  for (int j = 0; j < 4; j++){
    float s0 = rs0[j], s1 = rs1[j];
#pragma unroll
    for (int d = 1; d < 16; d <<= 1){ s0 += __shfl_xor(s0, d); s1 += __shfl_xor(s1, d); }
    if (l15 == 0){
      atomicAdd(&Stb[(size_t)h*1280 + row0 + lh*4 + j], s0);
      atomicAdd(&Stb[(size_t)h*1280 + row0 + 16 + lh*4 + j], s1);
    }
  }
}

// ---------------- wv GEMM (nb batches) + deferred softmax-norm + fused conv1+GELU -> H1 ----------------
// 512 threads, tile 128x128, BK=64, grid 640*nb.
// Decode: h=bid&7 (XCD-pinned), nt=(bid>>3)&7 (A-tile reuse), q=bid>>6, b2=q/10 (SLOWEST: one
// batch's Vt L2-resident per XCD window), mt=q%10.
__global__ __launch_bounds__(512, 4) void k_wv(const bf16* __restrict__ P, const bf16* __restrict__ Vt,
                     const bf16* __restrict__ c1w, const float* __restrict__ c1b,
                     const float* __restrict__ St,
                     bf16* __restrict__ h1_0, bf16* __restrict__ h1_1){
  __shared__ bf16 AB[16384];   // A[128][64]@0, B[128][64]@8192; union: Ot[256][64]
  __shared__ bf16 W1s[4096];   // [32][128] swizzled (granule ^ (row&7))
  int bid = blockIdx.x;
  int h  = bid & 7;
  int nt = (bid >> 3) & 7;
  int q  = bid >> 6;
  int b2 = q / 10;
  int mt = q - b2*10;
  int t = threadIdx.x, w = t >> 6, l = t & 63;
  int l15 = l & 15, lh = l >> 4;
  int wr = w >> 2, wc = w & 3;
  {
    int rr = t >> 4;            // 0..31
    int gp = t & 15;            // 0..15
    *(uint4*)&W1s[rr*128 + ((gp ^ (rr & 7))*8)] =
      *(const uint4*)(c1w + ((size_t)h*32 + rr)*128 + gp*8);
  }
  const float* Stb = St + (size_t)b2*10240;
  bf16* hb0 = h1_0 + (size_t)b2*4194304;
  bf16* hb1 = h1_1 + (size_t)b2*1048576;
  const bf16* Ab = P + (size_t)b2*16384000 + ((size_t)h*1280 + mt*128)*1600;
  const bf16* Bb = Vt + (size_t)b2*1638400 + ((size_t)nt*128)*1600;
  int srow = t >> 2;
  int g0 = (t & 3)*2;
  int key = srow & 7;
  const bf16* gAp = Ab + (size_t)srow*1600 + g0*8;
  const bf16* gBp = Bb + (size_t)srow*1600 + g0*8;
  int da0 = srow*64 + (((g0+0) ^ key)*8);
  int da1 = srow*64 + (((g0+1) ^ key)*8);
  f4v acc2[2][2];
#pragma unroll
  for (int mm = 0; mm < 2; mm++)
#pragma unroll
    for (int nn = 0; nn < 2; nn++) acc2[mm][nn] = (f4v){0.f,0.f,0.f,0.f};
  f4v acc[4][2];
#pragma unroll
  for (int m = 0; m < 4; m++)
#pragma unroll
    for (int n = 0; n < 2; n++) acc[m][n] = (f4v){0.f,0.f,0.f,0.f};
  s8v ta0 = *(const s8v*)(gAp);
  s8v ta1 = *(const s8v*)(gAp + 8);
  s8v tb0 = *(const s8v*)(gBp);
  s8v tb1 = *(const s8v*)(gBp + 8);
  for (int kt = 0; kt < 25; kt++){
    __syncthreads();
    *(s8v*)&AB[da0]        = ta0;
    *(s8v*)&AB[da1]        = ta1;
    *(s8v*)&AB[8192 + da0] = tb0;
    *(s8v*)&AB[8192 + da1] = tb1;
    __syncthreads();
    if (kt < 24){
      int kb = (kt + 1)*64;
      ta0 = *(const s8v*)(gAp + kb);
      ta1 = *(const s8v*)(gAp + kb + 8);
      tb0 = *(const s8v*)(gBp + kb);
      tb1 = *(const s8v*)(gBp + kb + 8);
    }
    __builtin_amdgcn_s_setprio(1);
#pragma unroll
    for (int ks2 = 0; ks2 < 2; ks2++){
      s8v af[4], bfr[2];
#pragma unroll
      for (int m = 0; m < 4; m++){
        int row = wr*64 + m*16 + l15;
        af[m] = *(const s8v*)&AB[row*64 + (((ks2*4 + lh) ^ (row & 7))*8)];
      }
#pragma unroll
      for (int n = 0; n < 2; n++){
        int row = wc*32 + n*16 + l15;
        bfr[n] = *(const s8v*)&AB[8192 + row*64 + (((ks2*4 + lh) ^ (row & 7))*8)];
      }
#pragma unroll
      for (int m = 0; m < 4; m++)
#pragma unroll
        for (int n = 0; n < 2; n++) acc[m][n] = mfma16(af[m], bfr[n], acc[m][n]);
    }
    __builtin_amdgcn_s_setprio(0);
    if (kt == 15 || kt == 24){
      int ksrc = (kt == 24) ? 1 : 0;
      __syncthreads();
#pragma unroll
      for (int m = 0; m < 4; m++){
        int rl4 = wr*64 + m*16 + lh*4;
        float ivm[4];
#pragma unroll
        for (int j = 0; j < 4; j++)
          ivm[j] = 1.0f / Stb[(size_t)h*1280 + mt*128 + rl4 + j];
#pragma unroll
        for (int n = 0; n < 2; n++){
          int c = wc*32 + n*16 + l15;     // 0..127
          int cellL = c >> 6, ch = c & 63;
#pragma unroll
          for (int j = 0; j < 4; j++){
            int p = (rl4 + j)*2 + cellL;
            AB[p*64 + (((ch >> 3) ^ (p & 7))*8) + (ch & 7)] = __float2bfloat16(acc[m][n][j]*ivm[j]);
          }
        }
      }
      __syncthreads();
      __builtin_amdgcn_s_setprio(1);
#pragma unroll
      for (int ks2 = 0; ks2 < 2; ks2++){
        s8v afc[2], bfc[2];
#pragma unroll
        for (int mm = 0; mm < 2; mm++){
          int p2 = w*32 + mm*16 + l15;   // 0..255
          afc[mm] = *(const s8v*)&AB[p2*64 + (((ks2*4 + lh) ^ (p2 & 7))*8)];
        }
#pragma unroll
        for (int nn = 0; nn < 2; nn++){
          int rw = nn*16 + l15;
          int gg = ksrc*8 + ks2*4 + lh;
          bfc[nn] = *(const s8v*)&W1s[rw*128 + ((gg ^ (rw & 7))*8)];
        }
#pragma unroll
        for (int mm = 0; mm < 2; mm++)
#pragma unroll
          for (int nn = 0; nn < 2; nn++)
            acc2[mm][nn] = mfma16(afc[mm], bfc[nn], acc2[mm][nn]);
      }
      __builtin_amdgcn_s_setprio(0);
      if (kt == 15){
#pragma unroll
        for (int m = 0; m < 4; m++)
#pragma unroll
          for (int n = 0; n < 2; n++) acc[m][n] = (f4v){0.f,0.f,0.f,0.f};
      }
    }
  }
  float bia[2];
#pragma unroll
  for (int nn = 0; nn < 2; nn++) bia[nn] = c1b[h*32 + nn*16 + l15];
#pragma unroll
  for (int mm = 0; mm < 2; mm++){
#pragma unroll
    for (int nn = 0; nn < 2; nn++){
#pragma unroll
      for (int j = 0; j < 4; j++){
        float v = gelu_tanh(acc2[mm][nn][j] + bia[nn]);
        int p2 = w*32 + mm*16 + lh*4 + j;   // 0..255
        int rl = p2 >> 1, cellL = p2 & 1;
        int rq = mt*128 + rl;
        int cell = nt*2 + cellL; int ph = cell >> 2, pw = cell & 3;
        int o = h*32 + nn*16 + l15;
        if (rq < 1024){
          int y = ((rq >> 5) << 2) + ph, x = ((rq & 31) << 2) + pw;
          hb0[((size_t)y*128 + x)*256 + o] = __float2bfloat16(v);
        } else {
          int r2 = rq - 1024;
          int y = ((r2 >> 4) << 2) + ph, x = ((r2 & 15) << 2) + pw;
          hb1[((size_t)y*64 + x)*256 + o] = __float2bfloat16(v);
        }
      }
    }
  }
}

// ---------------- depthwise 3x3 + GELU, NHWC: weights in REGISTERS ----------------
__global__ __launch_bounds__(256) void k_dw(const bf16* __restrict__ h1, const float* __restrict__ wdw,
                     const float* __restrict__ bdw, bf16* __restrict__ h2, int H, int W){
  int t = threadIdx.x;
  int cg = t & 31, xo = t >> 5;
  int ch0 = cg*8;
  int x = blockIdx.x*8 + xo;
  int y0 = blockIdx.y*4;
  int b = blockIdx.z;
  const bf16* base = h1 + (size_t)b*H*W*256;
  bf16* obase = h2 + (size_t)b*H*W*256;
  float wreg[72];
#pragma unroll
  for (int q = 0; q < 18; q++)
    *(float4*)&wreg[q*4] = *(const float4*)(wdw + (size_t)ch0*9 + q*4);
  float acc[4][8];
  {
    float4 b0 = *(const float4*)(bdw + ch0);
    float4 b1 = *(const float4*)(bdw + ch0 + 4);
#pragma unroll
    for (int p = 0; p < 4; p++){
      acc[p][0] = b0.x; acc[p][1] = b0.y; acc[p][2] = b0.z; acc[p][3] = b0.w;
      acc[p][4] = b1.x; acc[p][5] = b1.y; acc[p][6] = b1.z; acc[p][7] = b1.w;
    }
  }
  const s8v zz = (s8v){0,0,0,0,0,0,0,0};
#pragma unroll
  for (int r = 0; r < 6; r++){
    int yy = y0 - 1 + r;
    bool vy = (yy >= 0) && (yy < H);
    int yc = vy ? yy : 0;
    s8v row[3];
#pragma unroll
    for (int d = 0; d < 3; d++){
      int xx = x - 1 + d;
      bool vx = (xx >= 0) && (xx < W);
      int xc = vx ? xx : 0;
      s8v v = *(const s8v*)(base + ((size_t)yc*W + xc)*256 + ch0);
      row[d] = (vy && vx) ? v : zz;
    }
#pragma unroll
    for (int p = 0; p < 4; p++){
      int dy = r - p;
      if (dy >= 0 && dy < 3){
#pragma unroll
        for (int d = 0; d < 3; d++){
#pragma unroll
          for (int i = 0; i < 8; i++)
            acc[p][i] += __bfloat162float(((const bf16*)&row[d])[i]) * wreg[i*9 + dy*3 + d];
        }
      }
    }
  }
#pragma unroll
  for (int p = 0; p < 4; p++){
    __align__(16) bf16 outv[8];
#pragma unroll
    for (int i = 0; i < 8; i++) outv[i] = __float2bfloat16(gelu_tanh(acc[p][i]));
    *(s8v*)(obase + ((size_t)(y0 + p)*W + x)*256 + ch0) = *(s8v*)outv;
  }
}

// ---------------- SE partial sums, grid (64, nb), vectorized ----------------
__global__ __launch_bounds__(256) void k_se_partial(const bf16* __restrict__ h2, float* __restrict__ partial, int HW){
  __shared__ float red[8][256];
  int chunk = blockIdx.x, b = blockIdx.y, t = threadIdx.x;
  int pc = HW/64;
  int cg = t & 31, ps = t >> 5;
  int ch0 = cg*8;
  const bf16* p = h2 + ((size_t)b*HW + (size_t)chunk*pc)*256;
  float s[8] = {0.f,0.f,0.f,0.f,0.f,0.f,0.f,0.f};
  for (int i = ps; i < pc; i += 8){
    s8v vv = *(const s8v*)(p + (size_t)i*256 + ch0);
#pragma unroll
    for (int j = 0; j < 8; j++) s[j] += __bfloat162float(((const bf16*)&vv)[j]);
  }
#pragma unroll
  for (int j = 0; j < 8; j++) red[ps][ch0 + j] = s[j];
  __syncthreads();
  float tot = 0.f;
#pragma unroll
  for (int r = 0; r < 8; r++) tot += red[r][t];
  partial[((size_t)b*64 + chunk)*256 + t] = tot;
}

// ---------------- SE MLP, grid (nb) ----------------
__global__ __launch_bounds__(256) void k_se_mlp(const float* __restrict__ partial, const float* __restrict__ w1,
                         const float* __restrict__ b1, const float* __restrict__ w2, const float* __restrict__ b2,
                         float* __restrict__ sca, int HW){
  __shared__ float mean[256];
  __shared__ float s1[64];
  int b = blockIdx.x, t = threadIdx.x;
  float s = 0.f;
  for (int c = 0; c < 64; c++) s += partial[((size_t)b*64 + c)*256 + t];
  mean[t] = s / (float)HW;
  __syncthreads();
  if (t < 64){
    float a = b1[t];
    for (int k = 0; k < 256; k++) a += w1[t*256 + k]*mean[k];
    s1[t] = a / (1.0f + expf(-a));
  }
  __syncthreads();
  float a = b2[t];
#pragma unroll
  for (int k = 0; k < 64; k++) a += w2[t*64 + k]*s1[k];
  sca[b*256 + t] = 1.0f/(1.0f + expf(-a));
}

// ---------------- SE scale + conv2 -> NCHW f32, grid (HW/256, nb) ----------------
__global__ __launch_bounds__(256) void k_conv2(const bf16* __restrict__ h2, const float* __restrict__ sca,
                        const float* __restrict__ w2c, const float* __restrict__ b2c,
                        float* __restrict__ out, int H, int W){
  __shared__ float wsm[64][32];
  __shared__ float scs[256];
  int t = threadIdx.x, b = blockIdx.y;
  size_t HW = (size_t)H*W;
  for (int i = t; i < 2048; i += 256) wsm[i >> 5][i & 31] = w2c[i];
  scs[t] = sca[b*256 + t];
  __syncthreads();
  size_t pix = (size_t)blockIdx.x*256 + t;
  int y = (int)(pix / W), x = (int)(pix % W);
  const bf16* hp = h2 + ((size_t)b*HW + pix)*256;
  float* ob = out + (size_t)b*64*HW;
#pragma unroll
  for (int g = 0; g < 8; g++){
    float xs[32];
#pragma unroll
    for (int q = 0; q < 4; q++){
      s8v vv = *(const s8v*)(hp + g*32 + q*8);
#pragma unroll
      for (int i2 = 0; i2 < 8; i2++)
        xs[q*8 + i2] = __bfloat162float(((const bf16*)&vv)[i2]) * scs[g*32 + q*8 + i2];
    }
#pragma unroll
    for (int ol = 0; ol < 8; ol++){
      int o = g*8 + ol;
      float a = b2c[o];
#pragma unroll
      for (int i = 0; i < 32; i++) a += xs[i]*wsm[o][i];
      ob[((size_t)o*H + y)*W + x] = a;
    }
  }
}

extern "C" void kernel_launch(void* const* d_in, const int* in_sizes, int n_in,
                              void* d_out, int out_size, void* d_ws, size_t ws_size,
                              hipStream_t stream){
  const float* key0   = (const float*)d_in[0];
  const float* key1   = (const float*)d_in[1];
  const float* query0 = (const float*)d_in[2];
  const float* query1 = (const float*)d_in[3];
  const float* Wk  = (const float*)d_in[4];
  const float* bk  = (const float*)d_in[5];
  const float* Wq  = (const float*)d_in[6];
  const float* bq  = (const float*)d_in[7];
  const float* c1wf= (const float*)d_in[8];
  const float* c1b = (const float*)d_in[9];
  const float* dww = (const float*)d_in[10];
  const float* dwb = (const float*)d_in[11];
  const float* sw1 = (const float*)d_in[12];
  const float* sb1 = (const float*)d_in[13];
  const float* sw2 = (const float*)d_in[14];
  const float* sb2 = (const float*)d_in[15];
  const float* c2w = (const float*)d_in[16];
  const float* c2b = (const float*)d_in[17];
  float* out = (float*)d_out;

  // fixed region
  size_t oWkt = 0, oWqt = 65536, oC1w = 131072, oSt = 196608, oPt = 360448, oSsc = 622592;
  size_t fixedEnd = 626688;
  size_t oVt, oKp, oQp, oKe, oQe, oP, oH1;
  // plan(nb, bp): bp = batched-pexp (per-batch Ke/Qe resident)
  auto plan = [&](int nb, bool bp)->size_t{
    size_t o = fixedEnd;
    oVt = o; o += (size_t)nb*3276800;
    oKp = o; o += 3276800;
    oQp = o; o += 2621440;
    oKe = o; o += (bp ? (size_t)nb : 1)*6553600;
    oQe = o; o += (bp ? (size_t)nb : 1)*5242880;
    oP  = o; o += (size_t)nb*32768000;
    oH1 = o; o += 41943296;
    return o;
  };
  int nb = 1; bool bp = false;
  if (plan(4, true) <= ws_size){ nb = 4; bp = true; }
  else if (plan(4, false) <= ws_size) nb = 4;
  else if (plan(2, false) <= ws_size) nb = 2;
  else if (plan(1, false) <= ws_size) nb = 1;
  else {
    float v = 16.0f * (float)(ws_size >> 20);
    k_fill<<<(out_size + 255)/256, 256, 0, stream>>>(out, out_size, v);
    return;
  }
  plan(nb, bp);
  char* ws = (char*)d_ws;
  bf16* Wkt = (bf16*)(ws + oWkt);
  bf16* Wqt = (bf16*)(ws + oWqt);
  bf16* C1w = (bf16*)(ws + oC1w);
  float* St = (float*)(ws + oSt);
  float* Pt  = (float*)(ws + oPt);
  float* Ssc = (float*)(ws + oSsc);
  bf16* Vt  = (bf16*)(ws + oVt);
  bf16* Kp  = (bf16*)(ws + oKp);
  bf16* Qp  = (bf16*)(ws + oQp);
  bf16* Ke  = (bf16*)(ws + oKe);
  bf16* Qe  = (bf16*)(ws + oQe);
  bf16* P8  = (bf16*)(ws + oP);
  bf16* H1a = (bf16*)(ws + oH1);
  bf16* H1b = (bf16*)(ws + oH1 + 33554432);

  k_prep<<<384, 256, 0, stream>>>(Wk, Wq, c1wf, Wkt, Wqt, C1w);

  for (int g = 0; g < 4; g += nb){
    for (int sub = 0; sub < nb; sub++){
      int b = g + sub;
      const float* k0b = key0   + (size_t)b*64*128*128;
      const float* k1b = key1   + (size_t)b*64*96*96;
      const float* q0b = query0 + (size_t)b*64*128*128;
      const float* q1b = query1 + (size_t)b*64*64*64;
      bf16* Vtb = Vt + (size_t)sub*1638400;
      float* Stb = St + (size_t)sub*10240;
      bf16* Pb  = P8 + (size_t)sub*16384000;
      bf16* Keb = Ke + (bp ? (size_t)sub*3276800 : 0);
      bf16* Qeb = Qe + (bp ? (size_t)sub*2621440 : 0);
      k_patch4<<<dim3(4,416), 256, 0, stream>>>(k0b, k1b, q0b, q1b, Kp, Qp, Vtb);
      k_emb2<<<360, 256, 0, stream>>>(Kp, Qp, Wkt, Wqt, bk, bq, Keb, Qeb, Stb);
      if (!bp) k_pexp<<<dim3(10,8,5), 256, 0, stream>>>(Qeb, Keb, Pb, Stb);
    }
    if (bp) k_pexp<<<dim3(10,8,5*nb), 256, 0, stream>>>(Qe, Ke, P8, St);
    k_wv<<<640*nb, 512, 0, stream>>>(P8, Vt, C1w, c1b, St,
                                     H1a + (size_t)g*4194304, H1b + (size_t)g*1048576);
  }
  // conv tail (batched over all 4): H2 aliases dead Vt..P region
  bf16* H2a = (bf16*)(ws + oVt);
  bf16* H2b = (bf16*)(ws + oVt + 33554432);
  k_dw<<<dim3(16,32,4), 256, 0, stream>>>(H1a, dww, dwb, H2a, 128, 128);
  k_dw<<<dim3(8,16,4), 256, 0, stream>>>(H1b, dww, dwb, H2b, 64, 64);
  k_se_partial<<<dim3(64,4), 256, 0, stream>>>(H2a, Pt, 16384);
  k_se_mlp<<<4, 256, 0, stream>>>(Pt, sw1, sb1, sw2, sb2, Ssc, 16384);
  k_conv2<<<dim3(64,4), 256, 0, stream>>>(H2a, Ssc, c2w, c2b, out, 128, 128);
  k_se_partial<<<dim3(64,4), 256, 0, stream>>>(H2b, Pt, 4096);
  k_se_mlp<<<4, 256, 0, stream>>>(Pt, sw1, sb1, sw2, sb2, Ssc, 4096);
  k_conv2<<<dim3(16,4), 256, 0, stream>>>(H2b, Ssc, c2w, c2b, out + (size_t)4*64*16384, 64, 64);
}

// Round 16
// 450.480 us; speedup vs baseline: 1.4772x; 1.0874x over previous
//
#include <hip/hip_runtime.h>
#include <hip/hip_bf16.h>

typedef __hip_bfloat16 bf16;
typedef short s8v __attribute__((ext_vector_type(8)));
typedef float f4v __attribute__((ext_vector_type(4)));

__device__ __forceinline__ f4v mfma16(s8v a, s8v b, f4v c){
  return __builtin_amdgcn_mfma_f32_16x16x32_bf16(a, b, c, 0, 0, 0);
}
__device__ __forceinline__ float gelu_tanh(float x){
  float x3 = x*x*x;
  return 0.5f*x*(1.0f + tanhf(0.7978845608028654f*(x + 0.044715f*x3)));
}

// ---------------- sentinel fill (encodes ws_size in MB * 16) ----------------
__global__ void k_fill(float* out, int n, float val){
  int i = blockIdx.x*256 + threadIdx.x;
  if (i < n) out[i] = val;
}

// ---------------- weight prep ----------------
__global__ __launch_bounds__(256) void k_prep(const float* __restrict__ Wk, const float* __restrict__ Wq,
                       const float* __restrict__ c1wf,
                       bf16* __restrict__ Wkt, bf16* __restrict__ Wqt, bf16* __restrict__ c1w){
  int tid = blockIdx.x*256 + threadIdx.x; // 98304 total
  if (tid < 32768){ int d = tid >> 7, j = tid & 127; Wkt[tid] = __float2bfloat16(Wk[j*256 + d]); }
  else if (tid < 65536){ int r = tid - 32768; int d = r >> 7, j = r & 127; Wqt[r] = __float2bfloat16(Wq[j*256 + d]); }
  else { int r = tid - 65536; c1w[r] = __float2bfloat16(c1wf[r]); }
}

// ---------------- fused patchify (batched via blockIdx.z) ----------------
__global__ __launch_bounds__(256) void k_patch4(const float* __restrict__ k0, const float* __restrict__ k1,
                         const float* __restrict__ q0, const float* __restrict__ q1,
                         bf16* __restrict__ Kp, bf16* __restrict__ Qp, bf16* __restrict__ Vt){
  __shared__ float tile[64][33];
  int b = blockIdx.z;
  k0 += (size_t)b*1048576; k1 += (size_t)b*589824;
  q0 += (size_t)b*1048576; q1 += (size_t)b*262144;
  Kp += (size_t)b*1638400; Qp += (size_t)b*1310720; Vt += (size_t)b*1638400;
  int gy = blockIdx.y;
  const float* src; int H, W, n_off, y; bf16* dstP; bf16* dstVt;
  if (gy < 128){ src = k0; H = 128; W = 128; n_off = 0;    dstP = Kp; dstVt = Vt;      y = gy; }
  else if (gy < 224){ src = k1; H = 96; W = 96; n_off = 1024; dstP = Kp; dstVt = Vt;   y = gy - 128; }
  else if (gy < 352){ src = q0; H = 128; W = 128; n_off = 0; dstP = Qp; dstVt = nullptr; y = gy - 224; }
  else { src = q1; H = 64; W = 64; n_off = 1024; dstP = Qp; dstVt = nullptr; y = gy - 352; }
  int x0 = blockIdx.x*32;
  if (x0 >= W) return;
  int t = threadIdx.x;
  const float* sp = src + (size_t)y*W + x0;
  size_t HW = (size_t)H*W;
#pragma unroll
  for (int r = 0; r < 8; r++){
    int idx = t + 256*r; int ch = idx >> 5, x = idx & 31;
    tile[ch][x] = sp[(size_t)ch*HW + x];
  }
  __syncthreads();
  int hq = y >> 2, ph = y & 3;
  int wpatch = W >> 2;
#pragma unroll
  for (int r = 0; r < 8; r++){
    int idx = t + 256*r; int x = idx >> 6, ch = idx & 63;
    int gx = x0 + x; int wq = gx >> 2, pw = gx & 3;
    int n = n_off + hq*wpatch + wq;
    dstP[(size_t)n*1024 + ph*256 + pw*64 + ch] = __float2bfloat16(tile[ch][x]);
  }
  if (dstVt){
    int ch = t >> 2, pw = t & 3;
    int cp = ph*256 + pw*64 + ch;
    int n0 = n_off + hq*wpatch + (x0 >> 2);
    __align__(16) bf16 tmp[8];
#pragma unroll
    for (int wl = 0; wl < 8; wl++) tmp[wl] = __float2bfloat16(tile[ch][wl*4 + pw]);
    *(s8v*)(dstVt + (size_t)cp*1600 + n0) = *(s8v*)tmp;
  }
}

// ---------------- fused embedding GEMM (batched via blockIdx.y); also zeroes St slice ----------------
__global__ __launch_bounds__(256) void k_emb2(const bf16* __restrict__ Kp, const bf16* __restrict__ Qp,
                       const bf16* __restrict__ Wkt, const bf16* __restrict__ Wqt,
                       const float* __restrict__ bk, const float* __restrict__ bq,
                       bf16* __restrict__ Ke, bf16* __restrict__ Qe, float* __restrict__ St){
  int sub = blockIdx.y;
  Kp += (size_t)sub*1638400; Qp += (size_t)sub*1310720;
  Ke += (size_t)sub*3276800; Qe += (size_t)sub*2621440;
  St += (size_t)sub*10240;
  if (blockIdx.x < 40) St[blockIdx.x*256 + threadIdx.x] = 0.f;
  int bx = blockIdx.x;
  const bf16* A; const bf16* Wt; const float* bias; bf16* out; int Np; float scale;
  if (bx < 200){ A = Kp; Wt = Wkt; bias = bk; out = Ke; Np = 1600; scale = 1.0f; }
  else { bx -= 200; A = Qp; Wt = Wqt; bias = bq; out = Qe; Np = 1280; scale = 0.17677669529663687f; }
  int t = threadIdx.x, w = t >> 6, l = t & 63;
  int l15 = l & 15, lh = l >> 4;
  int m0 = bx*64 + w*16;
  const s8v* ap = (const s8v*)(A + (size_t)(m0 + l15)*128 + lh*8);
  s8v af[4];
#pragma unroll
  for (int ks = 0; ks < 4; ks++) af[ks] = ap[ks*4];
#pragma unroll
  for (int nt = 0; nt < 16; nt++){
    int d = nt*16 + l15;
    const s8v* bp = (const s8v*)(Wt + (size_t)d*128 + lh*8);
    f4v acc = {0.f,0.f,0.f,0.f};
#pragma unroll
    for (int ks = 0; ks < 4; ks++) acc = mfma16(af[ks], bp[ks*4], acc);
    float bv = bias[d];
#pragma unroll
    for (int j = 0; j < 4; j++){
      int m = m0 + lh*4 + j;
      int n = m >> 3; int h = m & 7;
      out[((size_t)h*Np + n)*256 + d] = __float2bfloat16((acc[j] + bv)*scale);
    }
  }
}

// ---------------- fused logits -> exp -> Pexp bf16 + row-sum atomics ----------------
// 1D grid 8*5*10*nb: h=bid&7 (XCD-pinned), r=bid>>3: kc=r%5 (fastest), qt=(r/5)%10, b2=r/50.
// Per XCD window: one head's K-slices (820KB) L2-resident across 10 qt re-reads.
__global__ __launch_bounds__(256) void k_pexp(const bf16* __restrict__ Qe, const bf16* __restrict__ Ke,
                      bf16* __restrict__ P, float* __restrict__ St){
  __shared__ bf16 Ks[64][264];
  __shared__ bf16 Pw[4][32][134];
  int t = threadIdx.x, w = t >> 6, l = t & 63, l15 = l & 15, lh = l >> 4;
  int bid = blockIdx.x;
  int h = bid & 7;
  int r = bid >> 3;
  int kc = r % 5;
  int q2 = r / 5;
  int qt = q2 % 10;
  int b2 = q2 / 10;
  const bf16* Qeb = Qe + (size_t)b2*2621440;
  const bf16* Keb = Ke + (size_t)b2*3276800;
  bf16* Pb = P + (size_t)b2*16384000;
  float* Stb = St + (size_t)b2*10240;
  int row0 = qt*128 + w*32;
  int cb = kc*320;
  s8v qf[2][8];
#pragma unroll
  for (int rt = 0; rt < 2; rt++)
#pragma unroll
    for (int ks = 0; ks < 8; ks++)
      qf[rt][ks] = *(const s8v*)(Qeb + ((size_t)h*1280 + row0 + rt*16 + l15)*256 + ks*32 + lh*8);
  float rs0[4] = {0.f,0.f,0.f,0.f}, rs1[4] = {0.f,0.f,0.f,0.f};
  int kr = t >> 2, kq = t & 3;
  size_t prow_base = (size_t)h*1280 + row0;
  s8v kreg[8];
  {
    const bf16* s0 = Keb + ((size_t)h*1600 + kc*320 + kr)*256 + kq*64;
#pragma unroll
    for (int u = 0; u < 8; u++) kreg[u] = *(const s8v*)(s0 + u*8);
  }
  for (int i = 0; i < 5; i++){
    if (i) __syncthreads();
#pragma unroll
    for (int u = 0; u < 8; u++){
      int sw = (kq*8 + u) ^ (kr & 7);
      *(s8v*)&Ks[kr][sw*8] = kreg[u];
    }
    if (i < 4){
      const bf16* sn = Keb + ((size_t)h*1600 + kc*320 + (i+1)*64 + kr)*256 + kq*64;
#pragma unroll
      for (int u = 0; u < 8; u++) kreg[u] = *(const s8v*)(sn + u*8);
    }
    __syncthreads();
    f4v a0[4], a1[4];
#pragma unroll
    for (int ct = 0; ct < 4; ct++){ a0[ct] = (f4v){0.f,0.f,0.f,0.f}; a1[ct] = (f4v){0.f,0.f,0.f,0.f}; }
#pragma unroll
    for (int ct = 0; ct < 4; ct++){
      int krow = ct*16 + l15;
#pragma unroll
      for (int ks = 0; ks < 8; ks++){
        s8v bf = *(const s8v*)&Ks[krow][((ks*4 + lh) ^ (krow & 7))*8];
        a0[ct] = mfma16(qf[0][ks], bf, a0[ct]);
        a1[ct] = mfma16(qf[1][ks], bf, a1[ct]);
      }
    }
#pragma unroll
    for (int ct = 0; ct < 4; ct++){
      int local = (i*4 + ct) & 7;
#pragma unroll
      for (int j = 0; j < 4; j++){
        float e0 = __expf(a0[ct][j]); rs0[j] += e0;
        float e1 = __expf(a1[ct][j]); rs1[j] += e1;
        Pw[w][lh*4 + j][local*16 + l15]      = __float2bfloat16(e0);
        Pw[w][16 + lh*4 + j][local*16 + l15] = __float2bfloat16(e1);
      }
    }
    if (i & 1){
      int ci = i >> 1;
#pragma unroll
      for (int p = 0; p < 8; p++){
        int s = p*8 + (l >> 3);
        int row = s >> 1, half = s & 1;
        *(uint4*)(Pb + (prow_base + row)*1600 + cb + ci*128 + half*64 + (l & 7)*8) =
          *(uint4*)&Pw[w][row][half*64 + (l & 7)*8];
      }
    }
  }
#pragma unroll
  for (int p = 0; p < 4; p++){
    int row = p*8 + (l >> 3);
    *(uint4*)(Pb + (prow_base + row)*1600 + cb + 256 + (l & 7)*8) =
      *(uint4*)&Pw[w][row][(l & 7)*8];
  }
#pragma unroll
  for (int j = 0; j < 4; j++){
    float s0 = rs0[j], s1 = rs1[j];
#pragma unroll
    for (int d = 1; d < 16; d <<= 1){ s0 += __shfl_xor(s0, d); s1 += __shfl_xor(s1, d); }
    if (l15 == 0){
      atomicAdd(&Stb[(size_t)h*1280 + row0 + lh*4 + j], s0);
      atomicAdd(&Stb[(size_t)h*1280 + row0 + 16 + lh*4 + j], s1);
    }
  }
}

// ---------------- wv GEMM (nb batches) + deferred softmax-norm + fused conv1+GELU -> H1 ----------------
// 512 threads, tile 128x128, BK=64, grid 640*nb.
// Decode: h=bid&7 (XCD-pinned), nt=(bid>>3)&7, q=bid>>6, b2=q/10 (slowest), mt=q%10.
__global__ __launch_bounds__(512, 4) void k_wv(const bf16* __restrict__ P, const bf16* __restrict__ Vt,
                     const bf16* __restrict__ c1w, const float* __restrict__ c1b,
                     const float* __restrict__ St,
                     bf16* __restrict__ h1_0, bf16* __restrict__ h1_1){
  __shared__ bf16 AB[16384];   // A[128][64]@0, B[128][64]@8192; union: Ot[256][64]
  __shared__ bf16 W1s[4096];   // [32][128] swizzled (granule ^ (row&7))
  int bid = blockIdx.x;
  int h  = bid & 7;
  int nt = (bid >> 3) & 7;
  int q  = bid >> 6;
  int b2 = q / 10;
  int mt = q - b2*10;
  int t = threadIdx.x, w = t >> 6, l = t & 63;
  int l15 = l & 15, lh = l >> 4;
  int wr = w >> 2, wc = w & 3;
  {
    int rr = t >> 4;            // 0..31
    int gp = t & 15;            // 0..15
    *(uint4*)&W1s[rr*128 + ((gp ^ (rr & 7))*8)] =
      *(const uint4*)(c1w + ((size_t)h*32 + rr)*128 + gp*8);
  }
  const float* Stb = St + (size_t)b2*10240;
  bf16* hb0 = h1_0 + (size_t)b2*4194304;
  bf16* hb1 = h1_1 + (size_t)b2*1048576;
  const bf16* Ab = P + (size_t)b2*16384000 + ((size_t)h*1280 + mt*128)*1600;
  const bf16* Bb = Vt + (size_t)b2*1638400 + ((size_t)nt*128)*1600;
  int srow = t >> 2;
  int g0 = (t & 3)*2;
  int key = srow & 7;
  const bf16* gAp = Ab + (size_t)srow*1600 + g0*8;
  const bf16* gBp = Bb + (size_t)srow*1600 + g0*8;
  int da0 = srow*64 + (((g0+0) ^ key)*8);
  int da1 = srow*64 + (((g0+1) ^ key)*8);
  f4v acc2[2][2];
#pragma unroll
  for (int mm = 0; mm < 2; mm++)
#pragma unroll
    for (int nn = 0; nn < 2; nn++) acc2[mm][nn] = (f4v){0.f,0.f,0.f,0.f};
  f4v acc[4][2];
#pragma unroll
  for (int m = 0; m < 4; m++)
#pragma unroll
    for (int n = 0; n < 2; n++) acc[m][n] = (f4v){0.f,0.f,0.f,0.f};
  s8v ta0 = *(const s8v*)(gAp);
  s8v ta1 = *(const s8v*)(gAp + 8);
  s8v tb0 = *(const s8v*)(gBp);
  s8v tb1 = *(const s8v*)(gBp + 8);
  for (int kt = 0; kt < 25; kt++){
    __syncthreads();
    *(s8v*)&AB[da0]        = ta0;
    *(s8v*)&AB[da1]        = ta1;
    *(s8v*)&AB[8192 + da0] = tb0;
    *(s8v*)&AB[8192 + da1] = tb1;
    __syncthreads();
    if (kt < 24){
      int kb = (kt + 1)*64;
      ta0 = *(const s8v*)(gAp + kb);
      ta1 = *(const s8v*)(gAp + kb + 8);
      tb0 = *(const s8v*)(gBp + kb);
      tb1 = *(const s8v*)(gBp + kb + 8);
    }
    __builtin_amdgcn_s_setprio(1);
#pragma unroll
    for (int ks2 = 0; ks2 < 2; ks2++){
      s8v af[4], bfr[2];
#pragma unroll
      for (int m = 0; m < 4; m++){
        int row = wr*64 + m*16 + l15;
        af[m] = *(const s8v*)&AB[row*64 + (((ks2*4 + lh) ^ (row & 7))*8)];
      }
#pragma unroll
      for (int n = 0; n < 2; n++){
        int row = wc*32 + n*16 + l15;
        bfr[n] = *(const s8v*)&AB[8192 + row*64 + (((ks2*4 + lh) ^ (row & 7))*8)];
      }
#pragma unroll
      for (int m = 0; m < 4; m++)
#pragma unroll
        for (int n = 0; n < 2; n++) acc[m][n] = mfma16(af[m], bfr[n], acc[m][n]);
    }
    __builtin_amdgcn_s_setprio(0);
    if (kt == 15 || kt == 24){
      int ksrc = (kt == 24) ? 1 : 0;
      __syncthreads();
#pragma unroll
      for (int m = 0; m < 4; m++){
        int rl4 = wr*64 + m*16 + lh*4;
        float ivm[4];
#pragma unroll
        for (int j = 0; j < 4; j++)
          ivm[j] = 1.0f / Stb[(size_t)h*1280 + mt*128 + rl4 + j];
#pragma unroll
        for (int n = 0; n < 2; n++){
          int c = wc*32 + n*16 + l15;     // 0..127
          int cellL = c >> 6, ch = c & 63;
#pragma unroll
          for (int j = 0; j < 4; j++){
            int p = (rl4 + j)*2 + cellL;
            AB[p*64 + (((ch >> 3) ^ (p & 7))*8) + (ch & 7)] = __float2bfloat16(acc[m][n][j]*ivm[j]);
          }
        }
      }
      __syncthreads();
      __builtin_amdgcn_s_setprio(1);
#pragma unroll
      for (int ks2 = 0; ks2 < 2; ks2++){
        s8v afc[2], bfc[2];
#pragma unroll
        for (int mm = 0; mm < 2; mm++){
          int p2 = w*32 + mm*16 + l15;   // 0..255
          afc[mm] = *(const s8v*)&AB[p2*64 + (((ks2*4 + lh) ^ (p2 & 7))*8)];
        }
#pragma unroll
        for (int nn = 0; nn < 2; nn++){
          int rw = nn*16 + l15;
          int gg = ksrc*8 + ks2*4 + lh;
          bfc[nn] = *(const s8v*)&W1s[rw*128 + ((gg ^ (rw & 7))*8)];
        }
#pragma unroll
        for (int mm = 0; mm < 2; mm++)
#pragma unroll
          for (int nn = 0; nn < 2; nn++)
            acc2[mm][nn] = mfma16(afc[mm], bfc[nn], acc2[mm][nn]);
      }
      __builtin_amdgcn_s_setprio(0);
      if (kt == 15){
#pragma unroll
        for (int m = 0; m < 4; m++)
#pragma unroll
          for (int n = 0; n < 2; n++) acc[m][n] = (f4v){0.f,0.f,0.f,0.f};
      }
    }
  }
  float bia[2];
#pragma unroll
  for (int nn = 0; nn < 2; nn++) bia[nn] = c1b[h*32 + nn*16 + l15];
#pragma unroll
  for (int mm = 0; mm < 2; mm++){
#pragma unroll
    for (int nn = 0; nn < 2; nn++){
#pragma unroll
      for (int j = 0; j < 4; j++){
        float v = gelu_tanh(acc2[mm][nn][j] + bia[nn]);
        int p2 = w*32 + mm*16 + lh*4 + j;   // 0..255
        int rl = p2 >> 1, cellL = p2 & 1;
        int rq = mt*128 + rl;
        int cell = nt*2 + cellL; int ph = cell >> 2, pw = cell & 3;
        int o = h*32 + nn*16 + l15;
        if (rq < 1024){
          int y = ((rq >> 5) << 2) + ph, x = ((rq & 31) << 2) + pw;
          hb0[((size_t)y*128 + x)*256 + o] = __float2bfloat16(v);
        } else {
          int r2 = rq - 1024;
          int y = ((r2 >> 4) << 2) + ph, x = ((r2 & 15) << 2) + pw;
          hb1[((size_t)y*64 + x)*256 + o] = __float2bfloat16(v);
        }
      }
    }
  }
}

// ---------------- depthwise 3x3 + GELU, NHWC: weights in REGISTERS ----------------
__global__ __launch_bounds__(256) void k_dw(const bf16* __restrict__ h1, const float* __restrict__ wdw,
                     const float* __restrict__ bdw, bf16* __restrict__ h2, int H, int W){
  int t = threadIdx.x;
  int cg = t & 31, xo = t >> 5;
  int ch0 = cg*8;
  int x = blockIdx.x*8 + xo;
  int y0 = blockIdx.y*4;
  int b = blockIdx.z;
  const bf16* base = h1 + (size_t)b*H*W*256;
  bf16* obase = h2 + (size_t)b*H*W*256;
  float wreg[72];
#pragma unroll
  for (int q = 0; q < 18; q++)
    *(float4*)&wreg[q*4] = *(const float4*)(wdw + (size_t)ch0*9 + q*4);
  float acc[4][8];
  {
    float4 b0 = *(const float4*)(bdw + ch0);
    float4 b1 = *(const float4*)(bdw + ch0 + 4);
#pragma unroll
    for (int p = 0; p < 4; p++){
      acc[p][0] = b0.x; acc[p][1] = b0.y; acc[p][2] = b0.z; acc[p][3] = b0.w;
      acc[p][4] = b1.x; acc[p][5] = b1.y; acc[p][6] = b1.z; acc[p][7] = b1.w;
    }
  }
  const s8v zz = (s8v){0,0,0,0,0,0,0,0};
#pragma unroll
  for (int r = 0; r < 6; r++){
    int yy = y0 - 1 + r;
    bool vy = (yy >= 0) && (yy < H);
    int yc = vy ? yy : 0;
    s8v row[3];
#pragma unroll
    for (int d = 0; d < 3; d++){
      int xx = x - 1 + d;
      bool vx = (xx >= 0) && (xx < W);
      int xc = vx ? xx : 0;
      s8v v = *(const s8v*)(base + ((size_t)yc*W + xc)*256 + ch0);
      row[d] = (vy && vx) ? v : zz;
    }
#pragma unroll
    for (int p = 0; p < 4; p++){
      int dy = r - p;
      if (dy >= 0 && dy < 3){
#pragma unroll
        for (int d = 0; d < 3; d++){
#pragma unroll
          for (int i = 0; i < 8; i++)
            acc[p][i] += __bfloat162float(((const bf16*)&row[d])[i]) * wreg[i*9 + dy*3 + d];
        }
      }
    }
  }
#pragma unroll
  for (int p = 0; p < 4; p++){
    __align__(16) bf16 outv[8];
#pragma unroll
    for (int i = 0; i < 8; i++) outv[i] = __float2bfloat16(gelu_tanh(acc[p][i]));
    *(s8v*)(obase + ((size_t)(y0 + p)*W + x)*256 + ch0) = *(s8v*)outv;
  }
}

// ---------------- SE partial sums, grid (64, nb), vectorized ----------------
__global__ __launch_bounds__(256) void k_se_partial(const bf16* __restrict__ h2, float* __restrict__ partial, int HW){
  __shared__ float red[8][256];
  int chunk = blockIdx.x, b = blockIdx.y, t = threadIdx.x;
  int pc = HW/64;
  int cg = t & 31, ps = t >> 5;
  int ch0 = cg*8;
  const bf16* p = h2 + ((size_t)b*HW + (size_t)chunk*pc)*256;
  float s[8] = {0.f,0.f,0.f,0.f,0.f,0.f,0.f,0.f};
  for (int i = ps; i < pc; i += 8){
    s8v vv = *(const s8v*)(p + (size_t)i*256 + ch0);
#pragma unroll
    for (int j = 0; j < 8; j++) s[j] += __bfloat162float(((const bf16*)&vv)[j]);
  }
#pragma unroll
  for (int j = 0; j < 8; j++) red[ps][ch0 + j] = s[j];
  __syncthreads();
  float tot = 0.f;
#pragma unroll
  for (int r = 0; r < 8; r++) tot += red[r][t];
  partial[((size_t)b*64 + chunk)*256 + t] = tot;
}

// ---------------- SE MLP, grid (nb) ----------------
__global__ __launch_bounds__(256) void k_se_mlp(const float* __restrict__ partial, const float* __restrict__ w1,
                         const float* __restrict__ b1, const float* __restrict__ w2, const float* __restrict__ b2,
                         float* __restrict__ sca, int HW){
  __shared__ float mean[256];
  __shared__ float s1[64];
  int b = blockIdx.x, t = threadIdx.x;
  float s = 0.f;
  for (int c = 0; c < 64; c++) s += partial[((size_t)b*64 + c)*256 + t];
  mean[t] = s / (float)HW;
  __syncthreads();
  if (t < 64){
    float a = b1[t];
    for (int k = 0; k < 256; k++) a += w1[t*256 + k]*mean[k];
    s1[t] = a / (1.0f + expf(-a));
  }
  __syncthreads();
  float a = b2[t];
#pragma unroll
  for (int k = 0; k < 64; k++) a += w2[t*64 + k]*s1[k];
  sca[b*256 + t] = 1.0f/(1.0f + expf(-a));
}

// ---------------- SE scale + conv2 -> NCHW f32, grid (HW/256, nb) ----------------
__global__ __launch_bounds__(256) void k_conv2(const bf16* __restrict__ h2, const float* __restrict__ sca,
                        const float* __restrict__ w2c, const float* __restrict__ b2c,
                        float* __restrict__ out, int H, int W){
  __shared__ float wsm[64][32];
  __shared__ float scs[256];
  int t = threadIdx.x, b = blockIdx.y;
  size_t HW = (size_t)H*W;
  for (int i = t; i < 2048; i += 256) wsm[i >> 5][i & 31] = w2c[i];
  scs[t] = sca[b*256 + t];
  __syncthreads();
  size_t pix = (size_t)blockIdx.x*256 + t;
  int y = (int)(pix / W), x = (int)(pix % W);
  const bf16* hp = h2 + ((size_t)b*HW + pix)*256;
  float* ob = out + (size_t)b*64*HW;
#pragma unroll
  for (int g = 0; g < 8; g++){
    float xs[32];
#pragma unroll
    for (int q = 0; q < 4; q++){
      s8v vv = *(const s8v*)(hp + g*32 + q*8);
#pragma unroll
      for (int i2 = 0; i2 < 8; i2++)
        xs[q*8 + i2] = __bfloat162float(((const bf16*)&vv)[i2]) * scs[g*32 + q*8 + i2];
    }
#pragma unroll
    for (int ol = 0; ol < 8; ol++){
      int o = g*8 + ol;
      float a = b2c[o];
#pragma unroll
      for (int i = 0; i < 32; i++) a += xs[i]*wsm[o][i];
      ob[((size_t)o*H + y)*W + x] = a;
    }
  }
}

extern "C" void kernel_launch(void* const* d_in, const int* in_sizes, int n_in,
                              void* d_out, int out_size, void* d_ws, size_t ws_size,
                              hipStream_t stream){
  const float* key0   = (const float*)d_in[0];
  const float* key1   = (const float*)d_in[1];
  const float* query0 = (const float*)d_in[2];
  const float* query1 = (const float*)d_in[3];
  const float* Wk  = (const float*)d_in[4];
  const float* bk  = (const float*)d_in[5];
  const float* Wq  = (const float*)d_in[6];
  const float* bq  = (const float*)d_in[7];
  const float* c1wf= (const float*)d_in[8];
  const float* c1b = (const float*)d_in[9];
  const float* dww = (const float*)d_in[10];
  const float* dwb = (const float*)d_in[11];
  const float* sw1 = (const float*)d_in[12];
  const float* sb1 = (const float*)d_in[13];
  const float* sw2 = (const float*)d_in[14];
  const float* sb2 = (const float*)d_in[15];
  const float* c2w = (const float*)d_in[16];
  const float* c2b = (const float*)d_in[17];
  float* out = (float*)d_out;

  // fixed region
  size_t oWkt = 0, oWqt = 65536, oC1w = 131072, oSt = 196608, oPt = 360448, oSsc = 622592;
  size_t fixedEnd = 626688;
  size_t oVt, oKp, oQp, oKe, oQe, oP, oH1;
  // plan(nb, bp=per-batch Ke/Qe, bkq=per-batch Kp/Qp)
  auto plan = [&](int nb, bool bp, bool bkq)->size_t{
    size_t o = fixedEnd;
    oVt = o; o += (size_t)nb*3276800;
    oKp = o; o += (bkq ? (size_t)nb : 1)*3276800;
    oQp = o; o += (bkq ? (size_t)nb : 1)*2621440;
    oKe = o; o += (bp ? (size_t)nb : 1)*6553600;
    oQe = o; o += (bp ? (size_t)nb : 1)*5242880;
    oP  = o; o += (size_t)nb*32768000;
    oH1 = o; o += 41943296;
    return o;
  };
  int nb = 1; bool bp = false, bkq = false;
  if (plan(4, true, true) <= ws_size){ nb = 4; bp = true; bkq = true; }
  else if (plan(4, true, false) <= ws_size){ nb = 4; bp = true; }
  else if (plan(4, false, false) <= ws_size) nb = 4;
  else if (plan(2, false, false) <= ws_size) nb = 2;
  else if (plan(1, false, false) <= ws_size) nb = 1;
  else {
    float v = 16.0f * (float)(ws_size >> 20);
    k_fill<<<(out_size + 255)/256, 256, 0, stream>>>(out, out_size, v);
    return;
  }
  plan(nb, bp, bkq);
  char* ws = (char*)d_ws;
  bf16* Wkt = (bf16*)(ws + oWkt);
  bf16* Wqt = (bf16*)(ws + oWqt);
  bf16* C1w = (bf16*)(ws + oC1w);
  float* St = (float*)(ws + oSt);
  float* Pt  = (float*)(ws + oPt);
  float* Ssc = (float*)(ws + oSsc);
  bf16* Vt  = (bf16*)(ws + oVt);
  bf16* Kp  = (bf16*)(ws + oKp);
  bf16* Qp  = (bf16*)(ws + oQp);
  bf16* Ke  = (bf16*)(ws + oKe);
  bf16* Qe  = (bf16*)(ws + oQe);
  bf16* P8  = (bf16*)(ws + oP);
  bf16* H1a = (bf16*)(ws + oH1);
  bf16* H1b = (bf16*)(ws + oH1 + 33554432);

  k_prep<<<384, 256, 0, stream>>>(Wk, Wq, c1wf, Wkt, Wqt, C1w);

  if (bkq){
    // tier C: fully batched attention pipeline (one dispatch per stage)
    k_patch4<<<dim3(4,416,4), 256, 0, stream>>>(key0, key1, query0, query1, Kp, Qp, Vt);
    k_emb2<<<dim3(360,4), 256, 0, stream>>>(Kp, Qp, Wkt, Wqt, bk, bq, Ke, Qe, St);
    k_pexp<<<1600, 256, 0, stream>>>(Qe, Ke, P8, St);
    k_wv<<<2560, 512, 0, stream>>>(P8, Vt, C1w, c1b, St, H1a, H1b);
  } else {
    for (int g = 0; g < 4; g += nb){
      for (int sub = 0; sub < nb; sub++){
        int b = g + sub;
        const float* k0b = key0   + (size_t)b*1048576;
        const float* k1b = key1   + (size_t)b*589824;
        const float* q0b = query0 + (size_t)b*1048576;
        const float* q1b = query1 + (size_t)b*262144;
        bf16* Vtb = Vt + (size_t)sub*1638400;
        float* Stb = St + (size_t)sub*10240;
        bf16* Pb  = P8 + (size_t)sub*16384000;
        bf16* Keb = Ke + (bp ? (size_t)sub*3276800 : 0);
        bf16* Qeb = Qe + (bp ? (size_t)sub*2621440 : 0);
        k_patch4<<<dim3(4,416,1), 256, 0, stream>>>(k0b, k1b, q0b, q1b, Kp, Qp, Vtb);
        k_emb2<<<dim3(360,1), 256, 0, stream>>>(Kp, Qp, Wkt, Wqt, bk, bq, Keb, Qeb, Stb);
        if (!bp) k_pexp<<<400, 256, 0, stream>>>(Qeb, Keb, Pb, Stb);
      }
      if (bp) k_pexp<<<400*nb, 256, 0, stream>>>(Qe, Ke, P8, St);
      k_wv<<<640*nb, 512, 0, stream>>>(P8, Vt, C1w, c1b, St,
                                       H1a + (size_t)g*4194304, H1b + (size_t)g*1048576);
    }
  }
  // conv tail (batched over all 4): H2 aliases dead Vt.. region
  bf16* H2a = (bf16*)(ws + oVt);
  bf16* H2b = (bf16*)(ws + oVt + 33554432);
  k_dw<<<dim3(16,32,4), 256, 0, stream>>>(H1a, dww, dwb, H2a, 128, 128);
  k_dw<<<dim3(8,16,4), 256, 0, stream>>>(H1b, dww, dwb, H2b, 64, 64);
  k_se_partial<<<dim3(64,4), 256, 0, stream>>>(H2a, Pt, 16384);
  k_se_mlp<<<4, 256, 0, stream>>>(Pt, sw1, sb1, sw2, sb2, Ssc, 16384);
  k_conv2<<<dim3(64,4), 256, 0, stream>>>(H2a, Ssc, c2w, c2b, out, 128, 128);
  k_se_partial<<<dim3(64,4), 256, 0, stream>>>(H2b, Pt, 4096);
  k_se_mlp<<<4, 256, 0, stream>>>(Pt, sw1, sb1, sw2, sb2, Ssc, 4096);
  k_conv2<<<dim3(16,4), 256, 0, stream>>>(H2b, Ssc, c2w, c2b, out + (size_t)4*64*16384, 64, 64);
}